// Round 12
// baseline (1516.157 us; speedup 1.0000x reference)
//
#include <hip/hip_runtime.h>
#include <hip/hip_bf16.h>
#include <stdint.h>

#define HW 192
#define PLANE (HW * HW)
#define PH 194
#define PPG (PH * PH)      // 37636 granules per padded 8-ch plane
#define TS 16              // square spatial tile
#define HC 18              // halo cols/rows
#define HGR (HC * HC)      // 324 halo granules

typedef __attribute__((ext_vector_type(8))) short frag8;
typedef __attribute__((ext_vector_type(16))) float f32x16;
typedef unsigned short ushort_t;

__device__ __forceinline__ void split2(float v, ushort_t& h, ushort_t& l) {
    __hip_bfloat16 bh = __float2bfloat16(v);
    float hf = __bfloat162float(bh);
    __hip_bfloat16 bl = __float2bfloat16(v - hf);
    h = __builtin_bit_cast(ushort_t, bh);
    l = __builtin_bit_cast(ushort_t, bl);
}

// async 16B global->LDS copy: per-lane global src, wave-uniform LDS base (+lane*16)
__device__ __forceinline__ void gld_lds16(const ushort_t* g, ushort_t* s) {
    __builtin_amdgcn_global_load_lds(
        (const __attribute__((address_space(1))) uint32_t*)(const void*)g,
        (__attribute__((address_space(3))) uint32_t*)(void*)s, 16, 0, 0);
}

// W[O][C_IN][3][3] f32 -> wh/wl [NOB][NCHUNK][10][OTC+1][8] bf16.
// Tap-slot stride padded by 1 granule (16B) to break LDS bank aliasing between
// adjacent tap slots (t and t+1 read by lane halves simultaneously).
// Pad granule, tap slot 9, and o>=C_OUT are zero.
__global__ __launch_bounds__(256) void wtrans_kernel(
    const float* __restrict__ w, ushort_t* __restrict__ wh, ushort_t* __restrict__ wl,
    int C_IN, int C_OUT, int NCHUNK, int OTC, int total)
{
    for (int idx = blockIdx.x * 256 + threadIdx.x; idx < total; idx += gridDim.x * 256) {
        int ic = idx & 7;
        int g = idx >> 3;
        int o = g % (OTC + 1); g /= (OTC + 1);
        int t = g % 10;  g /= 10;
        int c8 = g % NCHUNK;
        int ob = g / NCHUNK;
        int og = ob * OTC + o;
        float v = 0.f;
        if (t < 9 && o < OTC && og < C_OUT)
            v = w[((size_t)og * C_IN + c8 * 8 + ic) * 9 + t];
        ushort_t h, l;
        split2(v, h, l);
        wh[idx] = h; wl[idx] = l;
    }
}

// fx [64][H][W] f32 -> padded hi/lo planes [8][PH][PH][8]
__global__ __launch_bounds__(256) void packfx_kernel(
    const float* __restrict__ src, ushort_t* __restrict__ dh, ushort_t* __restrict__ dl, int n)
{
    for (int idx = blockIdx.x * 256 + threadIdx.x; idx < n; idx += gridDim.x * 256) {
        int c = idx / PLANE;
        int p = idx - c * PLANE;
        int y = p / HW, x = p - y * HW;
        size_t di = ((size_t)(c >> 3) * PPG + (size_t)(y + 1) * PH + (x + 1)) * 8 + (c & 7);
        ushort_t h, l;
        split2(src[idx], h, l);
        dh[di] = h; dl[di] = l;
    }
}

// zero the 1-px borders of nchunks padded planes (both hi and lo tensors)
__global__ __launch_bounds__(256) void zborder_kernel(
    ushort_t* __restrict__ ph, ushort_t* __restrict__ pl, int nchunks)
{
    int total = nchunks * 772;
    for (int i = blockIdx.x * 256 + threadIdx.x; i < total; i += gridDim.x * 256) {
        int chunk = i / 772, b = i - chunk * 772;
        int y, x;
        if (b < 194)      { y = 0;   x = b; }
        else if (b < 388) { y = 193; x = b - 194; }
        else { int r = b - 388; y = 1 + (r >> 1); x = (r & 1) ? 193 : 0; }
        size_t g = ((size_t)chunk * PPG + (size_t)y * PH + x) * 8;
        uint4 z = make_uint4(0, 0, 0, 0);
        *(uint4*)&ph[g] = z;
        *(uint4*)&pl[g] = z;
    }
}

// 3x3 SAME conv via split-bf16 MFMA (32x32x16), double-buffered LDS prefetch.
// inh/inl: [NCHUNK][PH][PH][8] bf16 padded planes; wh/wl: [NOB][NCHUNK][10][OTC+1][8].
// Block: 128 thr (2 waves), 16x16 spatial tile, OTC out ch (NF = OTC/32 n-frags).
// Per wave: mf=4 m-frags (32 px each = 2 rows x 16 cols) -> 64 FLOP per LDS byte.
// K-step = 16 = 2 tap-slots x 8 ic; 10 tap-slots (slot 9 zero) -> 5 k-steps/chunk.
// 32x32x16 maps: A row / B col = lane&31; k-octet = lane>>5 (tap select); same
// contiguous-8 k-labeling both sides -> HW k-permutation cancels.
// C/D (HW-verified): col = lane&31, row m = (reg&3) + 8*(reg>>2) + 4*(lane>>5).
// NOTE: no min-waves hint (rounds 5/8: hint below acc footprint -> scratch spill).
template<int NCHUNK, int OTC, bool LAST>
__global__ __launch_bounds__(128) void conv_mfma(
    const ushort_t* __restrict__ inh, const ushort_t* __restrict__ inl,
    const ushort_t* __restrict__ wth, const ushort_t* __restrict__ wtl,
    const float* __restrict__ bias, int c_out,
    ushort_t* __restrict__ outh, ushort_t* __restrict__ outl, float* __restrict__ outf)
{
    constexpr int NF = OTC / 32;
    constexpr int WTG = OTC + 1;              // granules per tap slot (padded)
    constexpr int WGR = 10 * WTG;             // granules per weight slab
    constexpr int NWI = (WGR + 63) / 64;      // staging iters
    __shared__ ushort_t s_xh[2 * HGR * 8], s_xl[2 * HGR * 8];   // 2 x 5184 B each
    __shared__ ushort_t s_wh[2 * WGR * 8], s_wl[2 * WGR * 8];

    const int tid = threadIdx.x;
    const int wv = tid >> 6;          // 0..1
    const int lane = tid & 63;
    const int ln31 = lane & 31;       // A row (pixel) / B col (o) / D col
    const int lhalf = lane >> 5;      // k-octet -> tap select within k-step
    const int tx0 = (blockIdx.x % 12) * TS;
    const int ty0 = (blockIdx.x / 12) * TS;
    const int ob = blockIdx.y;

    // m-frag = 32 px = 2 rows x 16 cols; wave wv owns rows wv*8 .. wv*8+7 (4 m-frags)
    const int prow = ln31 >> 4;       // row within 2-row m-frag
    const int pcol = ln31 & 15;
    int pixbase[4];
    #pragma unroll
    for (int mf = 0; mf < 4; ++mf)
        pixbase[mf] = ((wv * 8 + mf * 2 + prow) * HC + pcol) * 8;

    // per-lane tap offset into halo + weight slot, per k-step
    int hof[5], wslot[5];
    #pragma unroll
    for (int ks = 0; ks < 5; ++ks) {
        int t = ks * 2 + lhalf;
        wslot[ks] = t;
        int te = t > 8 ? 8 : t;   // pad slot 9 reads tap8's (valid) address; B there is zero
        int dy = te >= 6 ? 2 : (te >= 3 ? 1 : 0);
        int dx = te - dy * 3;
        hof[ks] = (dy * HC + dx) * 8;
    }

    f32x16 acc[4][NF];
    #pragma unroll
    for (int mf = 0; mf < 4; ++mf)
        #pragma unroll
        for (int nf = 0; nf < NF; ++nf) {
            int o = ob * OTC + nf * 32 + ln31;
            float bv = (o < c_out) ? bias[o] : 0.f;
            #pragma unroll
            for (int r = 0; r < 16; ++r) acc[mf][nf][r] = bv;
        }

    const ushort_t* wbh = wth + (size_t)ob * NCHUNK * WGR * 8;
    const ushort_t* wbl = wtl + (size_t)ob * NCHUNK * WGR * 8;

    auto stage = [&](int buf, int c8) {
        const ushort_t* ih = inh + (size_t)c8 * PPG * 8;
        const ushort_t* il = inl + (size_t)c8 * PPG * 8;
        ushort_t* dxh = s_xh + buf * (HGR * 8);
        ushort_t* dxl = s_xl + buf * (HGR * 8);
        // halo: 324 granules in 6 x 64-lane iters (tail guarded)
        for (int j = wv; j < 6; j += 2) {
            int hg = j * 64 + lane;
            if (hg < HGR) {
                int r = hg / HC, c = hg - r * HC;
                size_t sg = ((size_t)(ty0 + r) * PH + (tx0 + c)) * 8;
                gld_lds16(&ih[sg], &dxh[j * 64 * 8]);
                gld_lds16(&il[sg], &dxl[j * 64 * 8]);
            }
        }
        const ushort_t* wch = wbh + (size_t)c8 * WGR * 8;
        const ushort_t* wcl = wbl + (size_t)c8 * WGR * 8;
        ushort_t* dwh = s_wh + buf * WGR * 8;
        ushort_t* dwl = s_wl + buf * WGR * 8;
        for (int j = wv; j < NWI; j += 2) {
            int g = j * 64 + lane;
            if (g < WGR) {
                gld_lds16(&wch[(size_t)g * 8], &dwh[j * 64 * 8]);
                gld_lds16(&wcl[(size_t)g * 8], &dwl[j * 64 * 8]);
            }
        }
    };

    stage(0, 0);
    __syncthreads();   // drains vmcnt -> buf0 ready

    int cur = 0;
    for (int c8 = 0; c8 < NCHUNK; ++c8) {
        if (c8 + 1 < NCHUNK) stage(cur ^ 1, c8 + 1);   // async prefetch, other buffer

        const ushort_t* xh = s_xh + cur * (HGR * 8);
        const ushort_t* xl = s_xl + cur * (HGR * 8);
        const ushort_t* wh = s_wh + cur * (WGR * 8);
        const ushort_t* wl = s_wl + cur * (WGR * 8);
        #pragma unroll
        for (int ks = 0; ks < 5; ++ks) {
            frag8 bh[NF], bl[NF];
            #pragma unroll
            for (int nf = 0; nf < NF; ++nf) {
                int a = (wslot[ks] * WTG + nf * 32 + ln31) * 8;
                bh[nf] = *(const frag8*)&wh[a];
                bl[nf] = *(const frag8*)&wl[a];
            }
            #pragma unroll
            for (int mf = 0; mf < 4; ++mf) {
                int abase = pixbase[mf] + hof[ks];
                frag8 ah = *(const frag8*)&xh[abase];
                frag8 al = *(const frag8*)&xl[abase];
                #pragma unroll
                for (int nf = 0; nf < NF; ++nf) {
                    acc[mf][nf] = __builtin_amdgcn_mfma_f32_32x32x16_bf16(ah, bh[nf], acc[mf][nf], 0, 0, 0);
                    acc[mf][nf] = __builtin_amdgcn_mfma_f32_32x32x16_bf16(ah, bl[nf], acc[mf][nf], 0, 0, 0);
                    acc[mf][nf] = __builtin_amdgcn_mfma_f32_32x32x16_bf16(al, bh[nf], acc[mf][nf], 0, 0, 0);
                }
            }
        }
        __syncthreads();   // joins waves on cur + drains prefetch vmcnt -> next buf ready
        cur ^= 1;
    }

    // ---- epilogue: reg j: m = (j&3) + 8*(j>>2) + 4*lhalf; y += m>>4, x = m&15 ----
    #pragma unroll
    for (int mf = 0; mf < 4; ++mf) {
        #pragma unroll
        for (int nf = 0; nf < NF; ++nf) {
            int o = ob * OTC + nf * 32 + ln31;
            if (o < c_out) {
                #pragma unroll
                for (int i = 0; i < 4; ++i) {   // reg quads j = 4i..4i+3 -> consecutive x
                    int gy = ty0 + wv * 8 + mf * 2 + (i >> 1);
                    int px = tx0 + (i & 1) * 8 + lhalf * 4;
                    if (LAST) {
                        float4 v = make_float4(acc[mf][nf][4 * i + 0], acc[mf][nf][4 * i + 1],
                                               acc[mf][nf][4 * i + 2], acc[mf][nf][4 * i + 3]);
                        *(float4*)&outf[(size_t)o * PLANE + gy * HW + px] = v;
                    } else {
                        size_t g0 = ((size_t)(o >> 3) * PPG + (size_t)(gy + 1) * PH + (px + 1)) * 8 + (o & 7);
                        #pragma unroll
                        for (int r = 0; r < 4; ++r) {
                            ushort_t h, l;
                            split2(acc[mf][nf][4 * i + r], h, l);
                            outh[g0 + (size_t)r * 8] = h;
                            outl[g0 + (size_t)r * 8] = l;
                        }
                    }
                }
            }
        }
    }
}

// One batch image. out[c,y,x] = sum_p ks[p*3+c, y, x] * xpad[c, y+p/5-2, x+p%5-2]
__global__ __launch_bounds__(256) void apply_kernel(
    const float* __restrict__ x, const float* __restrict__ ks,
    float* __restrict__ out)
{
    int tid = blockIdx.x * 256 + threadIdx.x;
    if (tid >= PLANE) return;
    int y = tid / HW;
    int xc = tid - y * HW;

    float acc[3] = {0.f, 0.f, 0.f};
    #pragma unroll
    for (int p = 0; p < 25; ++p) {
        const int di = p / 5, dj = p % 5;
        int yy = y + di - 2, xx = xc + dj - 2;
        bool inb = (yy >= 0 && yy < HW && xx >= 0 && xx < HW);
        #pragma unroll
        for (int c = 0; c < 3; ++c) {
            float kv = ks[((size_t)(p * 3 + c) * HW + y) * HW + xc];
            float xv = inb ? x[((size_t)c * HW + yy) * HW + xx] : 0.f;
            acc[c] = fmaf(kv, xv, acc[c]);
        }
    }
    #pragma unroll
    for (int c = 0; c < 3; ++c)
        out[((size_t)c * HW + y) * HW + xc] = acc[c];
}

extern "C" void kernel_launch(void* const* d_in, const int* in_sizes, int n_in,
                              void* d_out, int out_size, void* d_ws, size_t ws_size,
                              hipStream_t stream) {
    const float* feature_x = (const float*)d_in[0];
    const float* x  = (const float*)d_in[1];
    const float* W1 = (const float*)d_in[2];
    const float* b1 = (const float*)d_in[3];
    const float* W2 = (const float*)d_in[4];
    const float* b2 = (const float*)d_in[5];
    const float* W3 = (const float*)d_in[6];
    const float* b3 = (const float*)d_in[7];
    float* out = (float*)d_out;

    // workspace layout in ushort units, total ~92.5 MB
    const size_t PLN32 = (size_t)32 * PPG * 8;   // 9,634,816 ush
    const size_t PLN8  = (size_t)8 * PPG * 8;    // 2,408,704 ush
    const size_t W1SZ = (size_t)4 * 8  * 10 * 65 * 8;   // 166,400
    const size_t W2SZ = (size_t)4 * 32 * 10 * 65 * 8;   // 665,600
    const size_t W3SZ = (size_t)3 * 32 * 10 * 33 * 8;   // 253,440
    ushort_t* y1h = (ushort_t*)d_ws;
    ushort_t* y1l = y1h + PLN32;
    ushort_t* y2h = y1l + PLN32;
    ushort_t* y2l = y2h + PLN32;
    ushort_t* shared_r = y2l + PLN32;            // max(fxh+fxl, ks) = 5,529,600 ush
    ushort_t* fxh = shared_r;
    ushort_t* fxl = fxh + PLN8;
    float*    ks  = (float*)shared_r;            // [75][PLANE] f32, aliases fx
    ushort_t* w1h = shared_r + 5529600;
    ushort_t* w1l = w1h + W1SZ;
    ushort_t* w2h = w1l + W1SZ;
    ushort_t* w2l = w2h + W2SZ;
    ushort_t* w3h = w2l + W2SZ;
    ushort_t* w3l = w3h + W3SZ;

    dim3 blk256(256), blk128(128);
    // zero padded borders of y1/y2 once (epilogues only write interiors)
    zborder_kernel<<<97, blk256, 0, stream>>>(y1h, y1l, 32);
    zborder_kernel<<<97, blk256, 0, stream>>>(y2h, y2l, 32);
    // weight transforms (shared across batches)
    wtrans_kernel<<<256, blk256, 0, stream>>>(W1, w1h, w1l, 64, 256, 8, 64, (int)W1SZ);
    wtrans_kernel<<<256, blk256, 0, stream>>>(W2, w2h, w2l, 256, 256, 32, 64, (int)W2SZ);
    wtrans_kernel<<<256, blk256, 0, stream>>>(W3, w3h, w3l, 256, 75, 32, 32, (int)W3SZ);

    // 16x16 tiles: 12 x 12 = 144 spatial blocks
    dim3 g12(144, 4), g3(144, 3), ga((PLANE + 255) / 256);
    for (int b = 0; b < 4; ++b) {
        const float* fx_b = feature_x + (size_t)b * 64 * PLANE;
        const float* x_b  = x + (size_t)b * 3 * PLANE;
        float* out_b      = out + (size_t)b * 3 * PLANE;
        packfx_kernel<<<1024, blk256, 0, stream>>>(fx_b, fxh, fxl, 64 * PLANE);
        zborder_kernel<<<25, blk256, 0, stream>>>(fxh, fxl, 8);   // ks aliasing clobbers fx borders
        conv_mfma< 8, 64, false><<<g12, blk128, 0, stream>>>(fxh, fxl, w1h, w1l, b1, 256, y1h, y1l, nullptr);
        conv_mfma<32, 64, false><<<g12, blk128, 0, stream>>>(y1h, y1l, w2h, w2l, b2, 256, y2h, y2l, nullptr);
        conv_mfma<32, 32, true ><<<g3,  blk128, 0, stream>>>(y2h, y2l, w3h, w3l, b3,  75, nullptr, nullptr, ks);
        apply_kernel<<<ga, blk256, 0, stream>>>(x_b, ks, out_b);
    }
}

// Round 13
// 1465.826 us; speedup vs baseline: 1.0343x; 1.0343x over previous
//
#include <hip/hip_runtime.h>
#include <hip/hip_bf16.h>
#include <stdint.h>

#define HW 192
#define PLANE (HW * HW)
#define PH 194
#define PPG (PH * PH)      // 37636 granules per padded 8-ch plane
#define TSX 32             // tile cols
#define TSY 16             // tile rows
#define HALC 34            // halo cols
#define HALR 18            // halo rows
#define HGR (HALR * HALC)  // 612 halo granules

typedef __attribute__((ext_vector_type(8))) short frag8;
typedef __attribute__((ext_vector_type(16))) float f32x16;
typedef unsigned short ushort_t;

__device__ __forceinline__ void split2(float v, ushort_t& h, ushort_t& l) {
    __hip_bfloat16 bh = __float2bfloat16(v);
    float hf = __bfloat162float(bh);
    __hip_bfloat16 bl = __float2bfloat16(v - hf);
    h = __builtin_bit_cast(ushort_t, bh);
    l = __builtin_bit_cast(ushort_t, bl);
}

// async 16B global->LDS copy: per-lane global src, wave-uniform LDS base (+lane*16)
__device__ __forceinline__ void gld_lds16(const ushort_t* g, ushort_t* s) {
    __builtin_amdgcn_global_load_lds(
        (const __attribute__((address_space(1))) uint32_t*)(const void*)g,
        (__attribute__((address_space(3))) uint32_t*)(void*)s, 16, 0, 0);
}

// W[O][C_IN][3][3] f32 -> wh/wl [NOB][NCHUNK][10][OTC][8] bf16 (tap slot 9 and o>=C_OUT zero)
__global__ __launch_bounds__(256) void wtrans_kernel(
    const float* __restrict__ w, ushort_t* __restrict__ wh, ushort_t* __restrict__ wl,
    int C_IN, int C_OUT, int NCHUNK, int OTC, int total)
{
    for (int idx = blockIdx.x * 256 + threadIdx.x; idx < total; idx += gridDim.x * 256) {
        int ic = idx & 7;
        int g = idx >> 3;
        int o = g % OTC; g /= OTC;
        int t = g % 10;  g /= 10;
        int c8 = g % NCHUNK;
        int ob = g / NCHUNK;
        int og = ob * OTC + o;
        float v = 0.f;
        if (t < 9 && og < C_OUT)
            v = w[((size_t)og * C_IN + c8 * 8 + ic) * 9 + t];
        ushort_t h, l;
        split2(v, h, l);
        wh[idx] = h; wl[idx] = l;
    }
}

// fx [64][H][W] f32 -> padded hi/lo planes [8][PH][PH][8]
__global__ __launch_bounds__(256) void packfx_kernel(
    const float* __restrict__ src, ushort_t* __restrict__ dh, ushort_t* __restrict__ dl, int n)
{
    for (int idx = blockIdx.x * 256 + threadIdx.x; idx < n; idx += gridDim.x * 256) {
        int c = idx / PLANE;
        int p = idx - c * PLANE;
        int y = p / HW, x = p - y * HW;
        size_t di = ((size_t)(c >> 3) * PPG + (size_t)(y + 1) * PH + (x + 1)) * 8 + (c & 7);
        ushort_t h, l;
        split2(src[idx], h, l);
        dh[di] = h; dl[di] = l;
    }
}

// zero the 1-px borders of nchunks padded planes (both hi and lo tensors)
__global__ __launch_bounds__(256) void zborder_kernel(
    ushort_t* __restrict__ ph, ushort_t* __restrict__ pl, int nchunks)
{
    int total = nchunks * 772;
    for (int i = blockIdx.x * 256 + threadIdx.x; i < total; i += gridDim.x * 256) {
        int chunk = i / 772, b = i - chunk * 772;
        int y, x;
        if (b < 194)      { y = 0;   x = b; }
        else if (b < 388) { y = 193; x = b - 194; }
        else { int r = b - 388; y = 1 + (r >> 1); x = (r & 1) ? 193 : 0; }
        size_t g = ((size_t)chunk * PPG + (size_t)y * PH + x) * 8;
        uint4 z = make_uint4(0, 0, 0, 0);
        *(uint4*)&ph[g] = z;
        *(uint4*)&pl[g] = z;
    }
}

// 3x3 SAME conv via split-bf16 MFMA (32x32x16), halo double-buffer + weight
// single-buffer. inh/inl: [NCHUNK][PH][PH][8]; wh/wl: [NOB][NCHUNK][10][OTC][8].
// Block: 256 thr (4 waves), 16(rows)x32(cols) tile. Wave wv owns rows wv*4..wv*4+3,
// each an m-frag of 32 px = ONE ROW (A-reads: 32 consecutive granules per half-wave,
// tap-shifted halves broadcast-overlap -> conflict-free, unlike 2-row frags (r11/12)).
// K-step = 16 = 2 tap-slots x 8 ic; 10 tap-slots (slot 9 zero) -> 5 k-steps/chunk.
// A row / B col = lane&31; k-octet = lane>>5 (tap); same contiguous-8 k-labeling
// both sides -> HW k-permutation cancels. C/D: col=lane&31, m=(reg&3)+8(reg>>2)+4(lane>>5).
// NOTE: no min-waves hint (rounds 5/8: hint below acc footprint -> scratch spill).
template<int NCHUNK, int OTC, bool LAST>
__global__ __launch_bounds__(256) void conv_mfma(
    const ushort_t* __restrict__ inh, const ushort_t* __restrict__ inl,
    const ushort_t* __restrict__ wth, const ushort_t* __restrict__ wtl,
    const float* __restrict__ bias, int c_out,
    ushort_t* __restrict__ outh, ushort_t* __restrict__ outl, float* __restrict__ outf)
{
    constexpr int NF = OTC / 32;
    constexpr int WGR = 10 * OTC;             // weight granules per chunk slab
    constexpr int NWI = WGR / 64;             // weight staging iters (10 or 5)
    __shared__ ushort_t s_xh[2 * HGR * 8], s_xl[2 * HGR * 8];   // 2 x 9792 B each
    __shared__ ushort_t s_wh[WGR * 8], s_wl[WGR * 8];           // single-buffered

    const int tid = threadIdx.x;
    const int wv = tid >> 6;          // 0..3
    const int lane = tid & 63;
    const int ln31 = lane & 31;       // A row (pixel col) / B col (o) / D col
    const int lhalf = lane >> 5;      // k-octet -> tap select within k-step
    const int tx0 = (blockIdx.x % 6) * TSX;
    const int ty0 = (blockIdx.x / 6) * TSY;
    const int ob = blockIdx.y;

    // m-frag = one row of 32 px; wave wv owns rows wv*4 .. wv*4+3
    int pixbase[4];
    #pragma unroll
    for (int mf = 0; mf < 4; ++mf)
        pixbase[mf] = ((wv * 4 + mf) * HALC + ln31) * 8;

    // per-lane tap offset into halo + weight slot, per k-step
    int hof[5], wslot[5];
    #pragma unroll
    for (int ks = 0; ks < 5; ++ks) {
        int t = ks * 2 + lhalf;
        wslot[ks] = t;
        int te = t > 8 ? 8 : t;   // pad slot 9 reads tap8's (valid) address; B there is zero
        int dy = te >= 6 ? 2 : (te >= 3 ? 1 : 0);
        int dx = te - dy * 3;
        hof[ks] = (dy * HALC + dx) * 8;
    }

    f32x16 acc[4][NF];
    #pragma unroll
    for (int mf = 0; mf < 4; ++mf)
        #pragma unroll
        for (int nf = 0; nf < NF; ++nf) {
            int o = ob * OTC + nf * 32 + ln31;
            float bv = (o < c_out) ? bias[o] : 0.f;
            #pragma unroll
            for (int r = 0; r < 16; ++r) acc[mf][nf][r] = bv;
        }

    const ushort_t* wbh = wth + (size_t)ob * NCHUNK * WGR * 8;
    const ushort_t* wbl = wtl + (size_t)ob * NCHUNK * WGR * 8;

    auto stage_halo = [&](int buf, int c8) {
        const ushort_t* ih = inh + (size_t)c8 * PPG * 8;
        const ushort_t* il = inl + (size_t)c8 * PPG * 8;
        ushort_t* dxh = s_xh + buf * (HGR * 8);
        ushort_t* dxl = s_xl + buf * (HGR * 8);
        // 612 granules in 10 x 64-lane iters (last iter 36 lanes)
        for (int j = wv; j < 10; j += 4) {
            int hg = j * 64 + lane;
            if (hg < HGR) {
                int r = hg / HALC, c = hg - r * HALC;
                size_t sg = ((size_t)(ty0 + r) * PH + (tx0 + c)) * 8;
                gld_lds16(&ih[sg], &dxh[j * 64 * 8]);
                gld_lds16(&il[sg], &dxl[j * 64 * 8]);
            }
        }
    };
    auto stage_w = [&](int c8) {
        const ushort_t* wch = wbh + (size_t)c8 * WGR * 8;
        const ushort_t* wcl = wbl + (size_t)c8 * WGR * 8;
        for (int j = wv; j < NWI; j += 4) {
            gld_lds16(&wch[(j * 64 + lane) * 8], &s_wh[j * 64 * 8]);
            gld_lds16(&wcl[(j * 64 + lane) * 8], &s_wl[j * 64 * 8]);
        }
    };

    stage_halo(0, 0);
    stage_w(0);
    __syncthreads();   // drains vmcnt -> buf0 + weights ready

    int cur = 0;
    for (int c8 = 0; c8 < NCHUNK; ++c8) {
        if (c8 + 1 < NCHUNK) stage_halo(cur ^ 1, c8 + 1);   // async halo prefetch

        const ushort_t* xh = s_xh + cur * (HGR * 8);
        const ushort_t* xl = s_xl + cur * (HGR * 8);
        #pragma unroll
        for (int ks = 0; ks < 5; ++ks) {
            frag8 bh[NF], bl[NF];
            #pragma unroll
            for (int nf = 0; nf < NF; ++nf) {
                int a = (wslot[ks] * OTC + nf * 32 + ln31) * 8;
                bh[nf] = *(const frag8*)&s_wh[a];
                bl[nf] = *(const frag8*)&s_wl[a];
            }
            #pragma unroll
            for (int mf = 0; mf < 4; ++mf) {
                int abase = pixbase[mf] + hof[ks];
                frag8 ah = *(const frag8*)&xh[abase];
                frag8 al = *(const frag8*)&xl[abase];
                #pragma unroll
                for (int nf = 0; nf < NF; ++nf) {
                    acc[mf][nf] = __builtin_amdgcn_mfma_f32_32x32x16_bf16(ah, bh[nf], acc[mf][nf], 0, 0, 0);
                    acc[mf][nf] = __builtin_amdgcn_mfma_f32_32x32x16_bf16(ah, bl[nf], acc[mf][nf], 0, 0, 0);
                    acc[mf][nf] = __builtin_amdgcn_mfma_f32_32x32x16_bf16(al, bh[nf], acc[mf][nf], 0, 0, 0);
                }
            }
        }
        __syncthreads();   // w readers done + halo prefetch drained
        if (c8 + 1 < NCHUNK) {
            stage_w(c8 + 1);       // overwrite single weight slab
            __syncthreads();       // drains w-stage vmcnt -> weights ready
        }
        cur ^= 1;
    }

    // ---- epilogue: reg j=4i+r: m = 8i + 4*lhalf + r = px col; row = wv*4+mf ----
    #pragma unroll
    for (int mf = 0; mf < 4; ++mf) {
        int gy = ty0 + wv * 4 + mf;
        #pragma unroll
        for (int nf = 0; nf < NF; ++nf) {
            int o = ob * OTC + nf * 32 + ln31;
            if (o < c_out) {
                #pragma unroll
                for (int i = 0; i < 4; ++i) {
                    int px = tx0 + i * 8 + lhalf * 4;
                    if (LAST) {
                        float4 v = make_float4(acc[mf][nf][4 * i + 0], acc[mf][nf][4 * i + 1],
                                               acc[mf][nf][4 * i + 2], acc[mf][nf][4 * i + 3]);
                        *(float4*)&outf[(size_t)o * PLANE + gy * HW + px] = v;
                    } else {
                        size_t g0 = ((size_t)(o >> 3) * PPG + (size_t)(gy + 1) * PH + (px + 1)) * 8 + (o & 7);
                        #pragma unroll
                        for (int r = 0; r < 4; ++r) {
                            ushort_t h, l;
                            split2(acc[mf][nf][4 * i + r], h, l);
                            outh[g0 + (size_t)r * 8] = h;
                            outl[g0 + (size_t)r * 8] = l;
                        }
                    }
                }
            }
        }
    }
}

// One batch image. out[c,y,x] = sum_p ks[p*3+c, y, x] * xpad[c, y+p/5-2, x+p%5-2]
__global__ __launch_bounds__(256) void apply_kernel(
    const float* __restrict__ x, const float* __restrict__ ks,
    float* __restrict__ out)
{
    int tid = blockIdx.x * 256 + threadIdx.x;
    if (tid >= PLANE) return;
    int y = tid / HW;
    int xc = tid - y * HW;

    float acc[3] = {0.f, 0.f, 0.f};
    #pragma unroll
    for (int p = 0; p < 25; ++p) {
        const int di = p / 5, dj = p % 5;
        int yy = y + di - 2, xx = xc + dj - 2;
        bool inb = (yy >= 0 && yy < HW && xx >= 0 && xx < HW);
        #pragma unroll
        for (int c = 0; c < 3; ++c) {
            float kv = ks[((size_t)(p * 3 + c) * HW + y) * HW + xc];
            float xv = inb ? x[((size_t)c * HW + yy) * HW + xx] : 0.f;
            acc[c] = fmaf(kv, xv, acc[c]);
        }
    }
    #pragma unroll
    for (int c = 0; c < 3; ++c)
        out[((size_t)c * HW + y) * HW + xc] = acc[c];
}

extern "C" void kernel_launch(void* const* d_in, const int* in_sizes, int n_in,
                              void* d_out, int out_size, void* d_ws, size_t ws_size,
                              hipStream_t stream) {
    const float* feature_x = (const float*)d_in[0];
    const float* x  = (const float*)d_in[1];
    const float* W1 = (const float*)d_in[2];
    const float* b1 = (const float*)d_in[3];
    const float* W2 = (const float*)d_in[4];
    const float* b2 = (const float*)d_in[5];
    const float* W3 = (const float*)d_in[6];
    const float* b3 = (const float*)d_in[7];
    float* out = (float*)d_out;

    // workspace layout in ushort units, total ~92.4 MB
    const size_t PLN32 = (size_t)32 * PPG * 8;   // 9,634,816 ush
    const size_t PLN8  = (size_t)8 * PPG * 8;    // 2,408,704 ush
    ushort_t* y1h = (ushort_t*)d_ws;
    ushort_t* y1l = y1h + PLN32;
    ushort_t* y2h = y1l + PLN32;
    ushort_t* y2l = y2h + PLN32;
    ushort_t* shared_r = y2l + PLN32;            // max(fxh+fxl, ks) = 5,529,600 ush
    ushort_t* fxh = shared_r;
    ushort_t* fxl = fxh + PLN8;
    float*    ks  = (float*)shared_r;            // [75][PLANE] f32, aliases fx
    ushort_t* w1h = shared_r + 5529600;          // [4][8][10][64][8]  = 163,840
    ushort_t* w1l = w1h + 163840;
    ushort_t* w2h = w1l + 163840;                // [4][32][10][64][8] = 655,360
    ushort_t* w2l = w2h + 655360;
    ushort_t* w3h = w2l + 655360;                // [3][32][10][32][8] = 245,760
    ushort_t* w3l = w3h + 245760;

    dim3 blk256(256);
    // zero padded borders of y1/y2 once (epilogues only write interiors)
    zborder_kernel<<<97, blk256, 0, stream>>>(y1h, y1l, 32);
    zborder_kernel<<<97, blk256, 0, stream>>>(y2h, y2l, 32);
    // weight transforms (shared across batches)
    wtrans_kernel<<<256, blk256, 0, stream>>>(W1, w1h, w1l, 64, 256, 8, 64, 163840);
    wtrans_kernel<<<256, blk256, 0, stream>>>(W2, w2h, w2l, 256, 256, 32, 64, 655360);
    wtrans_kernel<<<256, blk256, 0, stream>>>(W3, w3h, w3l, 256, 75, 32, 32, 245760);

    // 16x32 tiles: 6 x-tiles, 12 y-tiles = 72 spatial blocks
    dim3 g12(72, 4), g3(72, 3), ga((PLANE + 255) / 256);
    for (int b = 0; b < 4; ++b) {
        const float* fx_b = feature_x + (size_t)b * 64 * PLANE;
        const float* x_b  = x + (size_t)b * 3 * PLANE;
        float* out_b      = out + (size_t)b * 3 * PLANE;
        packfx_kernel<<<1024, blk256, 0, stream>>>(fx_b, fxh, fxl, 64 * PLANE);
        zborder_kernel<<<25, blk256, 0, stream>>>(fxh, fxl, 8);   // ks aliasing clobbers fx borders
        conv_mfma< 8, 64, false><<<g12, blk256, 0, stream>>>(fxh, fxl, w1h, w1l, b1, 256, y1h, y1l, nullptr);
        conv_mfma<32, 64, false><<<g12, blk256, 0, stream>>>(y1h, y1l, w2h, w2l, b2, 256, y2h, y2l, nullptr);
        conv_mfma<32, 32, true ><<<g3,  blk256, 0, stream>>>(y2h, y2l, w3h, w3l, b3,  75, nullptr, nullptr, ks);
        apply_kernel<<<ga, blk256, 0, stream>>>(x_b, ks, out_b);
    }
}

// Round 14
// 1117.600 us; speedup vs baseline: 1.3566x; 1.3116x over previous
//
#include <hip/hip_runtime.h>
#include <hip/hip_bf16.h>
#include <stdint.h>

#define HW 192
#define PLANE (HW * HW)
#define PH 194
#define PPG (PH * PH)      // 37636 granules per padded 8-ch plane
#define TSX 32             // tile cols
#define TSY 8              // tile rows
#define HALC 34            // halo cols
#define HALR 10            // halo rows
#define HGR (HALR * HALC)  // 340 halo granules

typedef __attribute__((ext_vector_type(8))) short frag8;
typedef __attribute__((ext_vector_type(16))) float f32x16;
typedef unsigned short ushort_t;

__device__ __forceinline__ void split2(float v, ushort_t& h, ushort_t& l) {
    __hip_bfloat16 bh = __float2bfloat16(v);
    float hf = __bfloat162float(bh);
    __hip_bfloat16 bl = __float2bfloat16(v - hf);
    h = __builtin_bit_cast(ushort_t, bh);
    l = __builtin_bit_cast(ushort_t, bl);
}

// async 16B global->LDS copy: per-lane global src, wave-uniform LDS base (+lane*16)
__device__ __forceinline__ void gld_lds16(const ushort_t* g, ushort_t* s) {
    __builtin_amdgcn_global_load_lds(
        (const __attribute__((address_space(1))) uint32_t*)(const void*)g,
        (__attribute__((address_space(3))) uint32_t*)(void*)s, 16, 0, 0);
}

// W[O][C_IN][3][3] f32 -> wh/wl [NOB][NCHUNK][10][OTC][8] bf16 (tap slot 9 and o>=C_OUT zero)
__global__ __launch_bounds__(256) void wtrans_kernel(
    const float* __restrict__ w, ushort_t* __restrict__ wh, ushort_t* __restrict__ wl,
    int C_IN, int C_OUT, int NCHUNK, int OTC, int total)
{
    for (int idx = blockIdx.x * 256 + threadIdx.x; idx < total; idx += gridDim.x * 256) {
        int ic = idx & 7;
        int g = idx >> 3;
        int o = g % OTC; g /= OTC;
        int t = g % 10;  g /= 10;
        int c8 = g % NCHUNK;
        int ob = g / NCHUNK;
        int og = ob * OTC + o;
        float v = 0.f;
        if (t < 9 && og < C_OUT)
            v = w[((size_t)og * C_IN + c8 * 8 + ic) * 9 + t];
        ushort_t h, l;
        split2(v, h, l);
        wh[idx] = h; wl[idx] = l;
    }
}

// fx [64][H][W] f32 -> padded hi/lo planes [8][PH][PH][8]
__global__ __launch_bounds__(256) void packfx_kernel(
    const float* __restrict__ src, ushort_t* __restrict__ dh, ushort_t* __restrict__ dl, int n)
{
    for (int idx = blockIdx.x * 256 + threadIdx.x; idx < n; idx += gridDim.x * 256) {
        int c = idx / PLANE;
        int p = idx - c * PLANE;
        int y = p / HW, x = p - y * HW;
        size_t di = ((size_t)(c >> 3) * PPG + (size_t)(y + 1) * PH + (x + 1)) * 8 + (c & 7);
        ushort_t h, l;
        split2(src[idx], h, l);
        dh[di] = h; dl[di] = l;
    }
}

// zero the 1-px borders of nchunks padded planes (both hi and lo tensors)
__global__ __launch_bounds__(256) void zborder_kernel(
    ushort_t* __restrict__ ph, ushort_t* __restrict__ pl, int nchunks)
{
    int total = nchunks * 772;
    for (int i = blockIdx.x * 256 + threadIdx.x; i < total; i += gridDim.x * 256) {
        int chunk = i / 772, b = i - chunk * 772;
        int y, x;
        if (b < 194)      { y = 0;   x = b; }
        else if (b < 388) { y = 193; x = b - 194; }
        else { int r = b - 388; y = 1 + (r >> 1); x = (r & 1) ? 193 : 0; }
        size_t g = ((size_t)chunk * PPG + (size_t)y * PH + x) * 8;
        uint4 z = make_uint4(0, 0, 0, 0);
        *(uint4*)&ph[g] = z;
        *(uint4*)&pl[g] = z;
    }
}

// 3x3 SAME conv via split-bf16 MFMA (32x32x16), halo + weight double-buffered,
// ONE barrier per chunk. inh/inl: [NCHUNK][PH][PH][8]; wh/wl: [NOB][NCHUNK][10][OTC][8].
// Block: 256 thr (4 waves), 8(rows)x32(cols) tile. Wave wv owns rows wv*2, wv*2+1;
// each row is an m-frag of 32 px (one-row frags -> conflict-free A-reads, r13-verified).
// K-step = 16 = 2 tap-slots x 8 ic; 10 tap-slots (slot 9 zero) -> 5 k-steps/chunk.
// A row / B col = lane&31; k-octet = lane>>5 (tap); same contiguous-8 k-labeling
// both sides -> HW k-permutation cancels. C/D: col=lane&31, m=(reg&3)+8(reg>>2)+4(lane>>5).
// NOTE: no min-waves hint (rounds 5/8: hint below acc footprint -> scratch spill).
template<int NCHUNK, int OTC, bool LAST>
__global__ __launch_bounds__(256) void conv_mfma(
    const ushort_t* __restrict__ inh, const ushort_t* __restrict__ inl,
    const ushort_t* __restrict__ wth, const ushort_t* __restrict__ wtl,
    const float* __restrict__ bias, int c_out,
    ushort_t* __restrict__ outh, ushort_t* __restrict__ outl, float* __restrict__ outf)
{
    constexpr int NF = OTC / 32;
    constexpr int WGR = 10 * OTC;             // weight granules per chunk slab
    constexpr int NWI = WGR / 64;             // weight staging iters (10 or 5)
    __shared__ ushort_t s_xh[2 * HGR * 8], s_xl[2 * HGR * 8];   // 2 x 5440 B each
    __shared__ ushort_t s_wh[2 * WGR * 8], s_wl[2 * WGR * 8];   // 2 x 10240 B each (OTC=64)

    const int tid = threadIdx.x;
    const int wv = tid >> 6;          // 0..3
    const int lane = tid & 63;
    const int ln31 = lane & 31;       // A row (pixel col) / B col (o) / D col
    const int lhalf = lane >> 5;      // k-octet -> tap select within k-step
    const int tx0 = (blockIdx.x % 6) * TSX;
    const int ty0 = (blockIdx.x / 6) * TSY;
    const int ob = blockIdx.y;

    // m-frag = one row of 32 px; wave wv owns rows wv*2 .. wv*2+1
    int pixbase[2];
    #pragma unroll
    for (int mf = 0; mf < 2; ++mf)
        pixbase[mf] = ((wv * 2 + mf) * HALC + ln31) * 8;

    // per-lane tap offset into halo + weight slot, per k-step
    int hof[5], wslot[5];
    #pragma unroll
    for (int ks = 0; ks < 5; ++ks) {
        int t = ks * 2 + lhalf;
        wslot[ks] = t;
        int te = t > 8 ? 8 : t;   // pad slot 9 reads tap8's (valid) address; B there is zero
        int dy = te >= 6 ? 2 : (te >= 3 ? 1 : 0);
        int dx = te - dy * 3;
        hof[ks] = (dy * HALC + dx) * 8;
    }

    f32x16 acc[2][NF];
    #pragma unroll
    for (int mf = 0; mf < 2; ++mf)
        #pragma unroll
        for (int nf = 0; nf < NF; ++nf) {
            int o = ob * OTC + nf * 32 + ln31;
            float bv = (o < c_out) ? bias[o] : 0.f;
            #pragma unroll
            for (int r = 0; r < 16; ++r) acc[mf][nf][r] = bv;
        }

    const ushort_t* wbh = wth + (size_t)ob * NCHUNK * WGR * 8;
    const ushort_t* wbl = wtl + (size_t)ob * NCHUNK * WGR * 8;

    auto stage = [&](int buf, int c8) {
        const ushort_t* ih = inh + (size_t)c8 * PPG * 8;
        const ushort_t* il = inl + (size_t)c8 * PPG * 8;
        ushort_t* dxh = s_xh + buf * (HGR * 8);
        ushort_t* dxl = s_xl + buf * (HGR * 8);
        // halo: 340 granules in 6 x 64-lane iters (last iter 20 lanes)
        for (int j = wv; j < 6; j += 4) {
            int hg = j * 64 + lane;
            if (hg < HGR) {
                int r = hg / HALC, c = hg - r * HALC;
                size_t sg = ((size_t)(ty0 + r) * PH + (tx0 + c)) * 8;
                gld_lds16(&ih[sg], &dxh[j * 64 * 8]);
                gld_lds16(&il[sg], &dxl[j * 64 * 8]);
            }
        }
        const ushort_t* wch = wbh + (size_t)c8 * WGR * 8;
        const ushort_t* wcl = wbl + (size_t)c8 * WGR * 8;
        ushort_t* dwh = s_wh + buf * (WGR * 8);
        ushort_t* dwl = s_wl + buf * (WGR * 8);
        for (int j = wv; j < NWI; j += 4) {
            gld_lds16(&wch[(j * 64 + lane) * 8], &dwh[j * 64 * 8]);
            gld_lds16(&wcl[(j * 64 + lane) * 8], &dwl[j * 64 * 8]);
        }
    };

    stage(0, 0);
    __syncthreads();   // drains vmcnt -> buf0 ready

    int cur = 0;
    for (int c8 = 0; c8 < NCHUNK; ++c8) {
        if (c8 + 1 < NCHUNK) stage(cur ^ 1, c8 + 1);   // async prefetch, other buffer

        const ushort_t* xh = s_xh + cur * (HGR * 8);
        const ushort_t* xl = s_xl + cur * (HGR * 8);
        const ushort_t* wh = s_wh + cur * (WGR * 8);
        const ushort_t* wl = s_wl + cur * (WGR * 8);
        #pragma unroll
        for (int ks = 0; ks < 5; ++ks) {
            frag8 bh[NF], bl[NF];
            #pragma unroll
            for (int nf = 0; nf < NF; ++nf) {
                int a = (wslot[ks] * OTC + nf * 32 + ln31) * 8;
                bh[nf] = *(const frag8*)&wh[a];
                bl[nf] = *(const frag8*)&wl[a];
            }
            #pragma unroll
            for (int mf = 0; mf < 2; ++mf) {
                int abase = pixbase[mf] + hof[ks];
                frag8 ah = *(const frag8*)&xh[abase];
                frag8 al = *(const frag8*)&xl[abase];
                #pragma unroll
                for (int nf = 0; nf < NF; ++nf) {
                    acc[mf][nf] = __builtin_amdgcn_mfma_f32_32x32x16_bf16(ah, bh[nf], acc[mf][nf], 0, 0, 0);
                    acc[mf][nf] = __builtin_amdgcn_mfma_f32_32x32x16_bf16(ah, bl[nf], acc[mf][nf], 0, 0, 0);
                    acc[mf][nf] = __builtin_amdgcn_mfma_f32_32x32x16_bf16(al, bh[nf], acc[mf][nf], 0, 0, 0);
                }
            }
        }
        __syncthreads();   // joins waves on cur + drains prefetch vmcnt -> next buf ready
        cur ^= 1;
    }

    // ---- epilogue: reg j=4i+r: px col m = 8i + 4*lhalf + r; row = wv*2+mf ----
    #pragma unroll
    for (int mf = 0; mf < 2; ++mf) {
        int gy = ty0 + wv * 2 + mf;
        #pragma unroll
        for (int nf = 0; nf < NF; ++nf) {
            int o = ob * OTC + nf * 32 + ln31;
            if (o < c_out) {
                #pragma unroll
                for (int i = 0; i < 4; ++i) {
                    int px = tx0 + i * 8 + lhalf * 4;
                    if (LAST) {
                        float4 v = make_float4(acc[mf][nf][4 * i + 0], acc[mf][nf][4 * i + 1],
                                               acc[mf][nf][4 * i + 2], acc[mf][nf][4 * i + 3]);
                        *(float4*)&outf[(size_t)o * PLANE + gy * HW + px] = v;
                    } else {
                        size_t g0 = ((size_t)(o >> 3) * PPG + (size_t)(gy + 1) * PH + (px + 1)) * 8 + (o & 7);
                        #pragma unroll
                        for (int r = 0; r < 4; ++r) {
                            ushort_t h, l;
                            split2(acc[mf][nf][4 * i + r], h, l);
                            outh[g0 + (size_t)r * 8] = h;
                            outl[g0 + (size_t)r * 8] = l;
                        }
                    }
                }
            }
        }
    }
}

// One batch image. out[c,y,x] = sum_p ks[p*3+c, y, x] * xpad[c, y+p/5-2, x+p%5-2]
__global__ __launch_bounds__(256) void apply_kernel(
    const float* __restrict__ x, const float* __restrict__ ks,
    float* __restrict__ out)
{
    int tid = blockIdx.x * 256 + threadIdx.x;
    if (tid >= PLANE) return;
    int y = tid / HW;
    int xc = tid - y * HW;

    float acc[3] = {0.f, 0.f, 0.f};
    #pragma unroll
    for (int p = 0; p < 25; ++p) {
        const int di = p / 5, dj = p % 5;
        int yy = y + di - 2, xx = xc + dj - 2;
        bool inb = (yy >= 0 && yy < HW && xx >= 0 && xx < HW);
        #pragma unroll
        for (int c = 0; c < 3; ++c) {
            float kv = ks[((size_t)(p * 3 + c) * HW + y) * HW + xc];
            float xv = inb ? x[((size_t)c * HW + yy) * HW + xx] : 0.f;
            acc[c] = fmaf(kv, xv, acc[c]);
        }
    }
    #pragma unroll
    for (int c = 0; c < 3; ++c)
        out[((size_t)c * HW + y) * HW + xc] = acc[c];
}

extern "C" void kernel_launch(void* const* d_in, const int* in_sizes, int n_in,
                              void* d_out, int out_size, void* d_ws, size_t ws_size,
                              hipStream_t stream) {
    const float* feature_x = (const float*)d_in[0];
    const float* x  = (const float*)d_in[1];
    const float* W1 = (const float*)d_in[2];
    const float* b1 = (const float*)d_in[3];
    const float* W2 = (const float*)d_in[4];
    const float* b2 = (const float*)d_in[5];
    const float* W3 = (const float*)d_in[6];
    const float* b3 = (const float*)d_in[7];
    float* out = (float*)d_out;

    // workspace layout in ushort units, total ~92.4 MB
    const size_t PLN32 = (size_t)32 * PPG * 8;   // 9,634,816 ush
    const size_t PLN8  = (size_t)8 * PPG * 8;    // 2,408,704 ush
    ushort_t* y1h = (ushort_t*)d_ws;
    ushort_t* y1l = y1h + PLN32;
    ushort_t* y2h = y1l + PLN32;
    ushort_t* y2l = y2h + PLN32;
    ushort_t* shared_r = y2l + PLN32;            // max(fxh+fxl, ks) = 5,529,600 ush
    ushort_t* fxh = shared_r;
    ushort_t* fxl = fxh + PLN8;
    float*    ks  = (float*)shared_r;            // [75][PLANE] f32, aliases fx
    ushort_t* w1h = shared_r + 5529600;          // [4][8][10][64][8]  = 163,840
    ushort_t* w1l = w1h + 163840;
    ushort_t* w2h = w1l + 163840;                // [4][32][10][64][8] = 655,360
    ushort_t* w2l = w2h + 655360;
    ushort_t* w3h = w2l + 655360;                // [3][32][10][32][8] = 245,760
    ushort_t* w3l = w3h + 245760;

    dim3 blk256(256);
    // zero padded borders of y1/y2 once (epilogues only write interiors)
    zborder_kernel<<<97, blk256, 0, stream>>>(y1h, y1l, 32);
    zborder_kernel<<<97, blk256, 0, stream>>>(y2h, y2l, 32);
    // weight transforms (shared across batches)
    wtrans_kernel<<<256, blk256, 0, stream>>>(W1, w1h, w1l, 64, 256, 8, 64, 163840);
    wtrans_kernel<<<256, blk256, 0, stream>>>(W2, w2h, w2l, 256, 256, 32, 64, 655360);
    wtrans_kernel<<<256, blk256, 0, stream>>>(W3, w3h, w3l, 256, 75, 32, 32, 245760);

    // 8x32 tiles: 6 x-tiles, 24 y-tiles = 144 spatial blocks; x4 ob = 576 blocks
    dim3 g12(144, 4), g3(144, 3), ga((PLANE + 255) / 256);
    for (int b = 0; b < 4; ++b) {
        const float* fx_b = feature_x + (size_t)b * 64 * PLANE;
        const float* x_b  = x + (size_t)b * 3 * PLANE;
        float* out_b      = out + (size_t)b * 3 * PLANE;
        packfx_kernel<<<1024, blk256, 0, stream>>>(fx_b, fxh, fxl, 64 * PLANE);
        zborder_kernel<<<25, blk256, 0, stream>>>(fxh, fxl, 8);   // ks aliasing clobbers fx borders
        conv_mfma< 8, 64, false><<<g12, blk256, 0, stream>>>(fxh, fxl, w1h, w1l, b1, 256, y1h, y1l, nullptr);
        conv_mfma<32, 64, false><<<g12, blk256, 0, stream>>>(y1h, y1l, w2h, w2l, b2, 256, y2h, y2l, nullptr);
        conv_mfma<32, 32, true ><<<g3,  blk256, 0, stream>>>(y2h, y2l, w3h, w3l, b3,  75, nullptr, nullptr, ks);
        apply_kernel<<<ga, blk256, 0, stream>>>(x_b, ks, out_b);
    }
}

// Round 16
// 1104.392 us; speedup vs baseline: 1.3728x; 1.0120x over previous
//
#include <hip/hip_runtime.h>
#include <hip/hip_bf16.h>
#include <stdint.h>

#define HW 192
#define PLANE (HW * HW)
#define PH 194
#define PPG (PH * PH)      // 37636 granules per padded 8-ch plane

typedef __attribute__((ext_vector_type(8))) short frag8;
typedef __attribute__((ext_vector_type(16))) float f32x16;
typedef unsigned short ushort_t;

__device__ __forceinline__ void split2(float v, ushort_t& h, ushort_t& l) {
    __hip_bfloat16 bh = __float2bfloat16(v);
    float hf = __bfloat162float(bh);
    __hip_bfloat16 bl = __float2bfloat16(v - hf);
    h = __builtin_bit_cast(ushort_t, bh);
    l = __builtin_bit_cast(ushort_t, bl);
}

// async 16B global->LDS copy: per-lane global src, wave-uniform LDS base (+lane*16)
__device__ __forceinline__ void gld_lds16(const ushort_t* g, ushort_t* s) {
    __builtin_amdgcn_global_load_lds(
        (const __attribute__((address_space(1))) uint32_t*)(const void*)g,
        (__attribute__((address_space(3))) uint32_t*)(void*)s, 16, 0, 0);
}

// W[O][C_IN][3][3] f32 -> wh/wl [NOB][NCHUNK][10][OTC][8] bf16 (tap slot 9 and o>=C_OUT zero)
__global__ __launch_bounds__(256) void wtrans_kernel(
    const float* __restrict__ w, ushort_t* __restrict__ wh, ushort_t* __restrict__ wl,
    int C_IN, int C_OUT, int NCHUNK, int OTC, int total)
{
    for (int idx = blockIdx.x * 256 + threadIdx.x; idx < total; idx += gridDim.x * 256) {
        int ic = idx & 7;
        int g = idx >> 3;
        int o = g % OTC; g /= OTC;
        int t = g % 10;  g /= 10;
        int c8 = g % NCHUNK;
        int ob = g / NCHUNK;
        int og = ob * OTC + o;
        float v = 0.f;
        if (t < 9 && og < C_OUT)
            v = w[((size_t)og * C_IN + c8 * 8 + ic) * 9 + t];
        ushort_t h, l;
        split2(v, h, l);
        wh[idx] = h; wl[idx] = l;
    }
}

// src [nb*64][H][W] f32 -> per-batch padded hi/lo planes [8][PH][PH][8] at b*bstr
__global__ __launch_bounds__(256) void packfx_kernel(
    const float* __restrict__ src, ushort_t* __restrict__ dh, ushort_t* __restrict__ dl,
    int nb, size_t bstr)
{
    int n = nb * 64 * PLANE;
    for (int idx = blockIdx.x * 256 + threadIdx.x; idx < n; idx += gridDim.x * 256) {
        int c = idx / PLANE;
        int p = idx - c * PLANE;
        int b = c >> 6, cc = c & 63;
        int y = p / HW, x = p - y * HW;
        size_t di = (size_t)b * bstr + ((size_t)(cc >> 3) * PPG + (size_t)(y + 1) * PH + (x + 1)) * 8 + (cc & 7);
        ushort_t h, l;
        split2(src[idx], h, l);
        dh[di] = h; dl[di] = l;
    }
}

// zero the 1-px borders of nchunks padded planes (both hi and lo tensors)
__global__ __launch_bounds__(256) void zborder_kernel(
    ushort_t* __restrict__ ph, ushort_t* __restrict__ pl, int nchunks)
{
    int total = nchunks * 772;
    for (int i = blockIdx.x * 256 + threadIdx.x; i < total; i += gridDim.x * 256) {
        int chunk = i / 772, b = i - chunk * 772;
        int y, x;
        if (b < 194)      { y = 0;   x = b; }
        else if (b < 388) { y = 193; x = b - 194; }
        else { int r = b - 388; y = 1 + (r >> 1); x = (r & 1) ? 193 : 0; }
        size_t g = ((size_t)chunk * PPG + (size_t)y * PH + x) * 8;
        uint4 z = make_uint4(0, 0, 0, 0);
        *(uint4*)&ph[g] = z;
        *(uint4*)&pl[g] = z;
    }
}

// 3x3 SAME conv via split-bf16 MFMA (32x32x16). blockIdx.z = batch within dispatch.
// inh/inl: [NCHUNK][PH][PH][8] per batch (stride in_bstr ush); wh/wl: [NOB][NCHUNK][10][OTC][8].
// Block: 256 thr (4 waves), (4*MF rows)x32 cols tile. Wave wv owns MF one-row m-frags
// (rows wv*MF..+MF-1); one-row frags are conflict-free A-reads (r13/r14-verified).
// MF==2: halo+weights double-buffered, one barrier/chunk (r14 structure, 62.7KB LDS).
// MF==4: halo double-buffered, weights single-buffered (59.6KB LDS), second barrier
//        exposes only the L2-hot weight stage (~400cy/chunk).
// K-step = 16 = 2 tap-slots x 8 ic; 10 tap-slots (slot 9 zero) -> 5 k-steps/chunk.
// A row / B col = lane&31; k-octet = lane>>5 (tap); same contiguous-8 k-labeling both
// sides -> HW k-permutation cancels. C/D: col=lane&31, m=(reg&3)+8(reg>>2)+4(lane>>5).
// NOTE: no min-waves hint (rounds 5/8: hint below acc footprint -> scratch spill).
template<int NCHUNK, int OTC, int MF, bool LAST>
__global__ __launch_bounds__(256) void conv_mfma(
    const ushort_t* __restrict__ inh, const ushort_t* __restrict__ inl,
    const ushort_t* __restrict__ wth, const ushort_t* __restrict__ wtl,
    const float* __restrict__ bias, int c_out,
    ushort_t* __restrict__ outh, ushort_t* __restrict__ outl, float* __restrict__ outf,
    size_t in_bstr, size_t out_bstr, size_t outf_bstr)
{
    constexpr int NF = OTC / 32;
    constexpr int TSY = 4 * MF;
    constexpr int HALR = TSY + 2;
    constexpr int HGR2 = HALR * 34;           // halo granules
    constexpr int NHI = (HGR2 + 63) / 64;     // halo staging iters
    constexpr int WGR = 10 * OTC;             // weight granules per chunk slab
    constexpr int NWI = WGR / 64;             // weight staging iters
    constexpr int WBUFS = (MF == 2) ? 2 : 1;  // weight buffers
    __shared__ ushort_t s_xh[2 * HGR2 * 8], s_xl[2 * HGR2 * 8];
    __shared__ ushort_t s_wh[WBUFS * WGR * 8], s_wl[WBUFS * WGR * 8];

    const int tid = threadIdx.x;
    const int wv = tid >> 6;          // 0..3
    const int lane = tid & 63;
    const int ln31 = lane & 31;       // A row (pixel col) / B col (o) / D col
    const int lhalf = lane >> 5;      // k-octet -> tap select within k-step
    const int tx0 = (blockIdx.x % 6) * 32;
    const int ty0 = (blockIdx.x / 6) * TSY;
    const int ob = blockIdx.y;
    const int bz = blockIdx.z;

    const ushort_t* binh = inh + (size_t)bz * in_bstr;
    const ushort_t* binl = inl + (size_t)bz * in_bstr;

    // m-frag = one row of 32 px; wave wv owns rows wv*MF .. wv*MF+MF-1
    int pixbase[MF];
    #pragma unroll
    for (int mf = 0; mf < MF; ++mf)
        pixbase[mf] = ((wv * MF + mf) * 34 + ln31) * 8;

    // per-lane tap offset into halo + weight slot, per k-step
    int hof[5], wslot[5];
    #pragma unroll
    for (int ks = 0; ks < 5; ++ks) {
        int t = ks * 2 + lhalf;
        wslot[ks] = t;
        int te = t > 8 ? 8 : t;   // pad slot 9 reads tap8's (valid) address; B there is zero
        int dy = te >= 6 ? 2 : (te >= 3 ? 1 : 0);
        int dx = te - dy * 3;
        hof[ks] = (dy * 34 + dx) * 8;
    }

    f32x16 acc[MF][NF];
    #pragma unroll
    for (int mf = 0; mf < MF; ++mf)
        #pragma unroll
        for (int nf = 0; nf < NF; ++nf) {
            int o = ob * OTC + nf * 32 + ln31;
            float bv = (o < c_out) ? bias[o] : 0.f;
            #pragma unroll
            for (int r = 0; r < 16; ++r) acc[mf][nf][r] = bv;
        }

    const ushort_t* wbh = wth + (size_t)ob * NCHUNK * WGR * 8;
    const ushort_t* wbl = wtl + (size_t)ob * NCHUNK * WGR * 8;

    auto stage_halo = [&](int buf, int c8) {
        const ushort_t* ih = binh + (size_t)c8 * PPG * 8;
        const ushort_t* il = binl + (size_t)c8 * PPG * 8;
        ushort_t* dxh = s_xh + buf * (HGR2 * 8);
        ushort_t* dxl = s_xl + buf * (HGR2 * 8);
        for (int j = wv; j < NHI; j += 4) {
            int hg = j * 64 + lane;
            if (hg < HGR2) {
                int r = hg / 34, c = hg - r * 34;
                size_t sg = ((size_t)(ty0 + r) * PH + (tx0 + c)) * 8;
                gld_lds16(&ih[sg], &dxh[j * 64 * 8]);
                gld_lds16(&il[sg], &dxl[j * 64 * 8]);
            }
        }
    };
    auto stage_w = [&](int buf, int c8) {
        const ushort_t* wch = wbh + (size_t)c8 * WGR * 8;
        const ushort_t* wcl = wbl + (size_t)c8 * WGR * 8;
        ushort_t* dwh = s_wh + (WBUFS == 2 ? buf * (WGR * 8) : 0);
        ushort_t* dwl = s_wl + (WBUFS == 2 ? buf * (WGR * 8) : 0);
        for (int j = wv; j < NWI; j += 4) {
            gld_lds16(&wch[(j * 64 + lane) * 8], &dwh[j * 64 * 8]);
            gld_lds16(&wcl[(j * 64 + lane) * 8], &dwl[j * 64 * 8]);
        }
    };

    stage_halo(0, 0);
    stage_w(0, 0);
    __syncthreads();   // drains vmcnt -> buf0 ready

    int cur = 0;
    for (int c8 = 0; c8 < NCHUNK; ++c8) {
        if (c8 + 1 < NCHUNK) {
            stage_halo(cur ^ 1, c8 + 1);            // async halo prefetch
            if constexpr (WBUFS == 2) stage_w(cur ^ 1, c8 + 1);
        }

        const ushort_t* xh = s_xh + cur * (HGR2 * 8);
        const ushort_t* xl = s_xl + cur * (HGR2 * 8);
        const ushort_t* wh = s_wh + (WBUFS == 2 ? cur * (WGR * 8) : 0);
        const ushort_t* wl = s_wl + (WBUFS == 2 ? cur * (WGR * 8) : 0);
        #pragma unroll
        for (int ks = 0; ks < 5; ++ks) {
            frag8 bh[NF], bl[NF];
            #pragma unroll
            for (int nf = 0; nf < NF; ++nf) {
                int a = (wslot[ks] * OTC + nf * 32 + ln31) * 8;
                bh[nf] = *(const frag8*)&wh[a];
                bl[nf] = *(const frag8*)&wl[a];
            }
            #pragma unroll
            for (int mf = 0; mf < MF; ++mf) {
                int abase = pixbase[mf] + hof[ks];
                frag8 ah = *(const frag8*)&xh[abase];
                frag8 al = *(const frag8*)&xl[abase];
                #pragma unroll
                for (int nf = 0; nf < NF; ++nf) {
                    acc[mf][nf] = __builtin_amdgcn_mfma_f32_32x32x16_bf16(ah, bh[nf], acc[mf][nf], 0, 0, 0);
                    acc[mf][nf] = __builtin_amdgcn_mfma_f32_32x32x16_bf16(ah, bl[nf], acc[mf][nf], 0, 0, 0);
                    acc[mf][nf] = __builtin_amdgcn_mfma_f32_32x32x16_bf16(al, bh[nf], acc[mf][nf], 0, 0, 0);
                }
            }
        }
        __syncthreads();   // compute(cur) done; halo(cur^1) prefetch drained
        if constexpr (WBUFS == 1) {
            if (c8 + 1 < NCHUNK) {
                stage_w(0, c8 + 1);    // overwrite single weight slab (L2-hot, ~400cy)
                __syncthreads();
            }
        }
        cur ^= 1;
    }

    // ---- epilogue: reg j=4i+r: px col m = 8i + 4*lhalf + r; row = wv*MF+mf ----
    #pragma unroll
    for (int mf = 0; mf < MF; ++mf) {
        int gy = ty0 + wv * MF + mf;
        #pragma unroll
        for (int nf = 0; nf < NF; ++nf) {
            int o = ob * OTC + nf * 32 + ln31;
            if (o < c_out) {
                #pragma unroll
                for (int i = 0; i < 4; ++i) {
                    int px = tx0 + i * 8 + lhalf * 4;
                    if constexpr (LAST) {
                        float* boutf = outf + (size_t)bz * outf_bstr;
                        float4 v = make_float4(acc[mf][nf][4 * i + 0], acc[mf][nf][4 * i + 1],
                                               acc[mf][nf][4 * i + 2], acc[mf][nf][4 * i + 3]);
                        *(float4*)&boutf[(size_t)o * PLANE + gy * HW + px] = v;
                    } else {
                        ushort_t* bouth = outh + (size_t)bz * out_bstr;
                        ushort_t* boutl = outl + (size_t)bz * out_bstr;
                        size_t g0 = ((size_t)(o >> 3) * PPG + (size_t)(gy + 1) * PH + (px + 1)) * 8 + (o & 7);
                        #pragma unroll
                        for (int r = 0; r < 4; ++r) {
                            ushort_t h, l;
                            split2(acc[mf][nf][4 * i + r], h, l);
                            bouth[g0 + (size_t)r * 8] = h;
                            boutl[g0 + (size_t)r * 8] = l;
                        }
                    }
                }
            }
        }
    }
}

// nb batches. out[b,c,y,x] = sum_p ks_b[p*3+c, y, x] * xpad[b, c, y+p/5-2, x+p%5-2]
__global__ __launch_bounds__(256) void apply_kernel(
    const float* __restrict__ x, const float* __restrict__ ks,
    float* __restrict__ out, int nb, size_t ks_bstr)
{
    int tid = blockIdx.x * 256 + threadIdx.x;
    int total = nb * PLANE;
    if (tid >= total) return;
    int b = tid / PLANE;
    int pix = tid - b * PLANE;
    int y = pix / HW;
    int xc = pix - y * HW;

    const float* xb  = x  + (size_t)b * 3 * PLANE;
    const float* ksb = ks + (size_t)b * ks_bstr;
    float* ob        = out + (size_t)b * 3 * PLANE;

    float acc[3] = {0.f, 0.f, 0.f};
    #pragma unroll
    for (int p = 0; p < 25; ++p) {
        const int di = p / 5, dj = p % 5;
        int yy = y + di - 2, xx = xc + dj - 2;
        bool inb = (yy >= 0 && yy < HW && xx >= 0 && xx < HW);
        #pragma unroll
        for (int c = 0; c < 3; ++c) {
            float kv = ksb[((size_t)(p * 3 + c) * HW + y) * HW + xc];
            float xv = inb ? xb[((size_t)c * HW + yy) * HW + xx] : 0.f;
            acc[c] = fmaf(kv, xv, acc[c]);
        }
    }
    #pragma unroll
    for (int c = 0; c < 3; ++c)
        ob[((size_t)c * HW + y) * HW + xc] = acc[c];
}

extern "C" void kernel_launch(void* const* d_in, const int* in_sizes, int n_in,
                              void* d_out, int out_size, void* d_ws, size_t ws_size,
                              hipStream_t stream) {
    const float* feature_x = (const float*)d_in[0];
    const float* x  = (const float*)d_in[1];
    const float* W1 = (const float*)d_in[2];
    const float* b1 = (const float*)d_in[3];
    const float* W2 = (const float*)d_in[4];
    const float* b2 = (const float*)d_in[5];
    const float* W3 = (const float*)d_in[6];
    const float* b3 = (const float*)d_in[7];
    float* out = (float*)d_out;

    const size_t PLN32 = (size_t)32 * PPG * 8;   // 9,634,816 ush
    const size_t PLN8  = (size_t)8 * PPG * 8;    // 2,408,704 ush
    const size_t Y_BSTR  = 2 * PLN32;            // batch stride (h+l) in y tensors
    const size_t FX_BSTR = 2 * PLN8;
    const size_t W1SZ = 163840, W2SZ = 655360, W3SZ = 245760;
    const size_t WTOT = 2 * (W1SZ + W2SZ + W3SZ);
    // 2-batch path: y1[2] + y2[2] + weights = 158,416,896 B
    const size_t FULLB = (8 * PLN32 + WTOT) * 2;
    const int NB = (ws_size >= FULLB) ? 2 : 1;

    size_t yreg = Y_BSTR * NB;
    ushort_t* y1 = (ushort_t*)d_ws;              // [NB][h|l][PLN32]
    ushort_t* y2 = y1 + yreg;
    ushort_t* wb = y2 + yreg;
    ushort_t* w1h = wb;            ushort_t* w1l = w1h + W1SZ;
    ushort_t* w2h = w1l + W1SZ;    ushort_t* w2l = w2h + W2SZ;
    ushort_t* w3h = w2l + W2SZ;    ushort_t* w3l = w3h + W3SZ;
    ushort_t* fxh = y2;            ushort_t* fxl = y2 + PLN8;    // fx aliases y2 region
    float*    ksf = (float*)y1;                                   // ks aliases y1 region

    dim3 blk(256);
    wtrans_kernel<<<256, blk, 0, stream>>>(W1, w1h, w1l, 64, 256, 8, 64, (int)W1SZ);
    wtrans_kernel<<<256, blk, 0, stream>>>(W2, w2h, w2l, 256, 256, 32, 64, (int)W2SZ);
    wtrans_kernel<<<256, blk, 0, stream>>>(W3, w3h, w3l, 256, 75, 32, 32, (int)W3SZ);

    if (NB == 2) {
        // MF=4: tile 16x32, grid 72 spatial x ob x 2 batches
        dim3 g12(72, 4, 2), g3(72, 3, 2), ga((2 * PLANE + 255) / 256);
        for (int bp = 0; bp < 2; ++bp) {
            const float* fxsrc = feature_x + (size_t)bp * 2 * 64 * PLANE;
            const float* x_b   = x   + (size_t)bp * 2 * 3 * PLANE;
            float* out_b       = out + (size_t)bp * 2 * 3 * PLANE;
            packfx_kernel<<<1024, blk, 0, stream>>>(fxsrc, fxh, fxl, 2, FX_BSTR);
            // Re-zero borders EVERY pair: prev pair's ks (aliasing y1) clobbered y1
            // borders with float bit patterns (bf16-NaN hazard, r15 bug). The y2
            // zborders also zero fx borders (fx overlays y2-batch0-h, same geometry).
            for (int b = 0; b < 2; ++b) {
                zborder_kernel<<<97, blk, 0, stream>>>(y1 + b * Y_BSTR, y1 + b * Y_BSTR + PLN32, 32);
                zborder_kernel<<<97, blk, 0, stream>>>(y2 + b * Y_BSTR, y2 + b * Y_BSTR + PLN32, 32);
            }
            conv_mfma< 8, 64, 4, false><<<g12, blk, 0, stream>>>(
                fxh, fxl, w1h, w1l, b1, 256, y1, y1 + PLN32, nullptr, FX_BSTR, Y_BSTR, 0);
            conv_mfma<32, 64, 4, false><<<g12, blk, 0, stream>>>(
                y1, y1 + PLN32, w2h, w2l, b2, 256, y2, y2 + PLN32, nullptr, Y_BSTR, Y_BSTR, 0);
            conv_mfma<32, 32, 4, true ><<<g3, blk, 0, stream>>>(
                y2, y2 + PLN32, w3h, w3l, b3, 75, nullptr, nullptr, ksf, Y_BSTR, 0, PLN32);
            apply_kernel<<<ga, blk, 0, stream>>>(x_b, ksf, out_b, 2, PLN32);
        }
    } else {
        // fallback: MF=2 (r14 structure), per-batch, tile 8x32, grid 144 spatial
        dim3 g12(144, 4, 1), g3(144, 3, 1), ga((PLANE + 255) / 256);
        for (int b = 0; b < 4; ++b) {
            const float* fx_b = feature_x + (size_t)b * 64 * PLANE;
            const float* x_b  = x + (size_t)b * 3 * PLANE;
            float* out_b      = out + (size_t)b * 3 * PLANE;
            packfx_kernel<<<1024, blk, 0, stream>>>(fx_b, fxh, fxl, 1, 0);
            // Re-zero EVERY batch (prev batch's ks clobbered y1 borders; y2 zborder
            // also zeroes fx borders since fx overlays y2h chunks 0..15).
            zborder_kernel<<<97, blk, 0, stream>>>(y1, y1 + PLN32, 32);
            zborder_kernel<<<97, blk, 0, stream>>>(y2, y2 + PLN32, 32);
            conv_mfma< 8, 64, 2, false><<<g12, blk, 0, stream>>>(
                fxh, fxl, w1h, w1l, b1, 256, y1, y1 + PLN32, nullptr, 0, 0, 0);
            conv_mfma<32, 64, 2, false><<<g12, blk, 0, stream>>>(
                y1, y1 + PLN32, w2h, w2l, b2, 256, y2, y2 + PLN32, nullptr, 0, 0, 0);
            conv_mfma<32, 32, 2, true ><<<g3, blk, 0, stream>>>(
                y2, y2 + PLN32, w3h, w3l, b3, 75, nullptr, nullptr, ksf, 0, 0, 0);
            apply_kernel<<<ga, blk, 0, stream>>>(x_b, ksf, out_b, 1, 0);
        }
    }
}

// Round 17
// 690.995 us; speedup vs baseline: 2.1942x; 1.5983x over previous
//
#include <hip/hip_runtime.h>
#include <hip/hip_bf16.h>
#include <stdint.h>

#define HW 192
#define PLANE (HW * HW)
#define PH 194
#define PPG (PH * PH)      // 37636 granules per padded 8-ch plane

typedef __attribute__((ext_vector_type(8))) short frag8;
typedef __attribute__((ext_vector_type(16))) float f32x16;
typedef unsigned short ushort_t;

__device__ __forceinline__ void split2(float v, ushort_t& h, ushort_t& l) {
    __hip_bfloat16 bh = __float2bfloat16(v);
    float hf = __bfloat162float(bh);
    __hip_bfloat16 bl = __float2bfloat16(v - hf);
    h = __builtin_bit_cast(ushort_t, bh);
    l = __builtin_bit_cast(ushort_t, bl);
}
__device__ __forceinline__ ushort_t b16(float v) {
    __hip_bfloat16 b = __float2bfloat16(v);
    return __builtin_bit_cast(ushort_t, b);
}

// async 16B global->LDS copy: per-lane global src, wave-uniform LDS base (+lane*16)
__device__ __forceinline__ void gld_lds16(const ushort_t* g, ushort_t* s) {
    __builtin_amdgcn_global_load_lds(
        (const __attribute__((address_space(1))) uint32_t*)(const void*)g,
        (__attribute__((address_space(3))) uint32_t*)(void*)s, 16, 0, 0);
}

// W[O][C_IN][3][3] f32 -> wh/wl [NOB][NCHUNK][10][OTC][8] bf16 (tap slot 9 and o>=C_OUT zero)
// Weights stay SPLIT (h+l) so weight precision is full; activations are plain bf16 (2-pass).
__global__ __launch_bounds__(256) void wtrans_kernel(
    const float* __restrict__ w, ushort_t* __restrict__ wh, ushort_t* __restrict__ wl,
    int C_IN, int C_OUT, int NCHUNK, int OTC, int total)
{
    for (int idx = blockIdx.x * 256 + threadIdx.x; idx < total; idx += gridDim.x * 256) {
        int ic = idx & 7;
        int g = idx >> 3;
        int o = g % OTC; g /= OTC;
        int t = g % 10;  g /= 10;
        int c8 = g % NCHUNK;
        int ob = g / NCHUNK;
        int og = ob * OTC + o;
        float v = 0.f;
        if (t < 9 && og < C_OUT)
            v = w[((size_t)og * C_IN + c8 * 8 + ic) * 9 + t];
        ushort_t h, l;
        split2(v, h, l);
        wh[idx] = h; wl[idx] = l;
    }
}

// src [nb*64][H][W] f32 -> per-batch padded bf16 planes [8][PH][PH][8] at b*bstr
__global__ __launch_bounds__(256) void packfx_kernel(
    const float* __restrict__ src, ushort_t* __restrict__ d,
    int nb, size_t bstr)
{
    int n = nb * 64 * PLANE;
    for (int idx = blockIdx.x * 256 + threadIdx.x; idx < n; idx += gridDim.x * 256) {
        int c = idx / PLANE;
        int p = idx - c * PLANE;
        int b = c >> 6, cc = c & 63;
        int y = p / HW, x = p - y * HW;
        size_t di = (size_t)b * bstr + ((size_t)(cc >> 3) * PPG + (size_t)(y + 1) * PH + (x + 1)) * 8 + (cc & 7);
        d[di] = b16(src[idx]);
    }
}

// zero the 1-px borders of nchunks padded planes
__global__ __launch_bounds__(256) void zborder_kernel(
    ushort_t* __restrict__ ph, int nchunks)
{
    int total = nchunks * 772;
    for (int i = blockIdx.x * 256 + threadIdx.x; i < total; i += gridDim.x * 256) {
        int chunk = i / 772, b = i - chunk * 772;
        int y, x;
        if (b < 194)      { y = 0;   x = b; }
        else if (b < 388) { y = 193; x = b - 194; }
        else { int r = b - 388; y = 1 + (r >> 1); x = (r & 1) ? 193 : 0; }
        size_t g = ((size_t)chunk * PPG + (size_t)y * PH + x) * 8;
        *(uint4*)&ph[g] = make_uint4(0, 0, 0, 0);
    }
}

// 3x3 SAME conv, 2-pass MFMA (32x32x16): A = bf16 activations (single plane),
// B = split weights; acc += A*wh + A*wl. blockIdx.z = batch within dispatch.
// inp: [NCHUNK][PH][PH][8] per batch (stride in_bstr ush); wh/wl: [NOB][NCHUNK][10][OTC][8].
// Block: 256 thr (4 waves), (4*MF rows)x32 cols tile. Wave wv owns MF one-row m-frags
// (rows wv*MF..+MF-1); one-row frags are conflict-free A-reads (r13/r14-verified).
// Halo + weights double-buffered, ONE barrier per chunk (60.5KB LDS at MF=4/OTC=64).
// K-step = 16 = 2 tap-slots x 8 ic; 10 tap-slots (slot 9 zero) -> 5 k-steps/chunk.
// A row / B col = lane&31; k-octet = lane>>5 (tap); same contiguous-8 k-labeling both
// sides -> HW k-permutation cancels. C/D: col=lane&31, m=(reg&3)+8(reg>>2)+4(lane>>5).
// NOTE: no min-waves hint (rounds 5/8: hint below acc footprint -> scratch spill).
template<int NCHUNK, int OTC, int MF, bool LAST>
__global__ __launch_bounds__(256) void conv_mfma(
    const ushort_t* __restrict__ inp,
    const ushort_t* __restrict__ wth, const ushort_t* __restrict__ wtl,
    const float* __restrict__ bias, int c_out,
    ushort_t* __restrict__ outp, float* __restrict__ outf,
    size_t in_bstr, size_t out_bstr, size_t outf_bstr)
{
    constexpr int NF = OTC / 32;
    constexpr int TSY = 4 * MF;
    constexpr int HALR = TSY + 2;
    constexpr int HGR2 = HALR * 34;           // halo granules
    constexpr int NHI = (HGR2 + 63) / 64;     // halo staging iters
    constexpr int WGR = 10 * OTC;             // weight granules per chunk slab
    constexpr int NWI = WGR / 64;             // weight staging iters
    __shared__ ushort_t s_x[2 * HGR2 * 8];
    __shared__ ushort_t s_wh[2 * WGR * 8], s_wl[2 * WGR * 8];

    const int tid = threadIdx.x;
    const int wv = tid >> 6;          // 0..3
    const int lane = tid & 63;
    const int ln31 = lane & 31;       // A row (pixel col) / B col (o) / D col
    const int lhalf = lane >> 5;      // k-octet -> tap select within k-step
    const int tx0 = (blockIdx.x % 6) * 32;
    const int ty0 = (blockIdx.x / 6) * TSY;
    const int ob = blockIdx.y;
    const int bz = blockIdx.z;

    const ushort_t* bin = inp + (size_t)bz * in_bstr;

    // m-frag = one row of 32 px; wave wv owns rows wv*MF .. wv*MF+MF-1
    int pixbase[MF];
    #pragma unroll
    for (int mf = 0; mf < MF; ++mf)
        pixbase[mf] = ((wv * MF + mf) * 34 + ln31) * 8;

    // per-lane tap offset into halo + weight slot, per k-step
    int hof[5], wslot[5];
    #pragma unroll
    for (int ks = 0; ks < 5; ++ks) {
        int t = ks * 2 + lhalf;
        wslot[ks] = t;
        int te = t > 8 ? 8 : t;   // pad slot 9 reads tap8's (valid) address; B there is zero
        int dy = te >= 6 ? 2 : (te >= 3 ? 1 : 0);
        int dx = te - dy * 3;
        hof[ks] = (dy * 34 + dx) * 8;
    }

    f32x16 acc[MF][NF];
    #pragma unroll
    for (int mf = 0; mf < MF; ++mf)
        #pragma unroll
        for (int nf = 0; nf < NF; ++nf) {
            int o = ob * OTC + nf * 32 + ln31;
            float bv = (o < c_out) ? bias[o] : 0.f;
            #pragma unroll
            for (int r = 0; r < 16; ++r) acc[mf][nf][r] = bv;
        }

    const ushort_t* wbh = wth + (size_t)ob * NCHUNK * WGR * 8;
    const ushort_t* wbl = wtl + (size_t)ob * NCHUNK * WGR * 8;

    auto stage = [&](int buf, int c8) {
        const ushort_t* ih = bin + (size_t)c8 * PPG * 8;
        ushort_t* dx = s_x + buf * (HGR2 * 8);
        for (int j = wv; j < NHI; j += 4) {
            int hg = j * 64 + lane;
            if (hg < HGR2) {
                int r = hg / 34, c = hg - r * 34;
                size_t sg = ((size_t)(ty0 + r) * PH + (tx0 + c)) * 8;
                gld_lds16(&ih[sg], &dx[j * 64 * 8]);
            }
        }
        const ushort_t* wch = wbh + (size_t)c8 * WGR * 8;
        const ushort_t* wcl = wbl + (size_t)c8 * WGR * 8;
        ushort_t* dwh = s_wh + buf * (WGR * 8);
        ushort_t* dwl = s_wl + buf * (WGR * 8);
        for (int j = wv; j < NWI; j += 4) {
            gld_lds16(&wch[(j * 64 + lane) * 8], &dwh[j * 64 * 8]);
            gld_lds16(&wcl[(j * 64 + lane) * 8], &dwl[j * 64 * 8]);
        }
    };

    stage(0, 0);
    __syncthreads();   // drains vmcnt -> buf0 ready

    int cur = 0;
    for (int c8 = 0; c8 < NCHUNK; ++c8) {
        if (c8 + 1 < NCHUNK) stage(cur ^ 1, c8 + 1);   // async prefetch, other buffer

        const ushort_t* xh = s_x + cur * (HGR2 * 8);
        const ushort_t* wh = s_wh + cur * (WGR * 8);
        const ushort_t* wl = s_wl + cur * (WGR * 8);
        #pragma unroll
        for (int ks = 0; ks < 5; ++ks) {
            frag8 bh[NF], bl[NF];
            #pragma unroll
            for (int nf = 0; nf < NF; ++nf) {
                int a = (wslot[ks] * OTC + nf * 32 + ln31) * 8;
                bh[nf] = *(const frag8*)&wh[a];
                bl[nf] = *(const frag8*)&wl[a];
            }
            #pragma unroll
            for (int mf = 0; mf < MF; ++mf) {
                frag8 ah = *(const frag8*)&xh[pixbase[mf] + hof[ks]];
                #pragma unroll
                for (int nf = 0; nf < NF; ++nf) {
                    acc[mf][nf] = __builtin_amdgcn_mfma_f32_32x32x16_bf16(ah, bh[nf], acc[mf][nf], 0, 0, 0);
                    acc[mf][nf] = __builtin_amdgcn_mfma_f32_32x32x16_bf16(ah, bl[nf], acc[mf][nf], 0, 0, 0);
                }
            }
        }
        __syncthreads();   // joins waves on cur + drains prefetch vmcnt -> next buf ready
        cur ^= 1;
    }

    // ---- epilogue: reg j=4i+r: px col m = 8i + 4*lhalf + r; row = wv*MF+mf ----
    #pragma unroll
    for (int mf = 0; mf < MF; ++mf) {
        int gy = ty0 + wv * MF + mf;
        #pragma unroll
        for (int nf = 0; nf < NF; ++nf) {
            int o = ob * OTC + nf * 32 + ln31;
            if (o < c_out) {
                #pragma unroll
                for (int i = 0; i < 4; ++i) {
                    int px = tx0 + i * 8 + lhalf * 4;
                    if constexpr (LAST) {
                        float* boutf = outf + (size_t)bz * outf_bstr;
                        float4 v = make_float4(acc[mf][nf][4 * i + 0], acc[mf][nf][4 * i + 1],
                                               acc[mf][nf][4 * i + 2], acc[mf][nf][4 * i + 3]);
                        *(float4*)&boutf[(size_t)o * PLANE + gy * HW + px] = v;
                    } else {
                        ushort_t* bout = outp + (size_t)bz * out_bstr;
                        size_t g0 = ((size_t)(o >> 3) * PPG + (size_t)(gy + 1) * PH + (px + 1)) * 8 + (o & 7);
                        #pragma unroll
                        for (int r = 0; r < 4; ++r)
                            bout[g0 + (size_t)r * 8] = b16(acc[mf][nf][4 * i + r]);
                    }
                }
            }
        }
    }
}

// nb batches. out[b,c,y,x] = sum_p ks_b[p*3+c, y, x] * xpad[b, c, y+p/5-2, x+p%5-2]
__global__ __launch_bounds__(256) void apply_kernel(
    const float* __restrict__ x, const float* __restrict__ ks,
    float* __restrict__ out, int nb, size_t ks_bstr)
{
    int tid = blockIdx.x * 256 + threadIdx.x;
    int total = nb * PLANE;
    if (tid >= total) return;
    int b = tid / PLANE;
    int pix = tid - b * PLANE;
    int y = pix / HW;
    int xc = pix - y * HW;

    const float* xb  = x  + (size_t)b * 3 * PLANE;
    const float* ksb = ks + (size_t)b * ks_bstr;
    float* ob        = out + (size_t)b * 3 * PLANE;

    float acc[3] = {0.f, 0.f, 0.f};
    #pragma unroll
    for (int p = 0; p < 25; ++p) {
        const int di = p / 5, dj = p % 5;
        int yy = y + di - 2, xx = xc + dj - 2;
        bool inb = (yy >= 0 && yy < HW && xx >= 0 && xx < HW);
        #pragma unroll
        for (int c = 0; c < 3; ++c) {
            float kv = ksb[((size_t)(p * 3 + c) * HW + y) * HW + xc];
            float xv = inb ? xb[((size_t)c * HW + yy) * HW + xx] : 0.f;
            acc[c] = fmaf(kv, xv, acc[c]);
        }
    }
    #pragma unroll
    for (int c = 0; c < 3; ++c)
        ob[((size_t)c * HW + y) * HW + xc] = acc[c];
}

extern "C" void kernel_launch(void* const* d_in, const int* in_sizes, int n_in,
                              void* d_out, int out_size, void* d_ws, size_t ws_size,
                              hipStream_t stream) {
    const float* feature_x = (const float*)d_in[0];
    const float* x  = (const float*)d_in[1];
    const float* W1 = (const float*)d_in[2];
    const float* b1 = (const float*)d_in[3];
    const float* W2 = (const float*)d_in[4];
    const float* b2 = (const float*)d_in[5];
    const float* W3 = (const float*)d_in[6];
    const float* b3 = (const float*)d_in[7];
    float* out = (float*)d_out;

    const size_t PLN32 = (size_t)32 * PPG * 8;   // 9,634,816 ush (single bf16 plane/batch)
    const size_t PLN8  = (size_t)8 * PPG * 8;    // 2,408,704 ush
    const size_t W1SZ = 163840, W2SZ = 655360, W3SZ = 245760;
    const size_t WTOT = W1SZ + W2SZ + W3SZ;      // 1,064,960 ush (x2 for h+l)
    // NB=4: y1[4] + y2[4] + weights = 158,416,896 B (PROVEN available in r16).
    const size_t FULL4 = (8 * PLN32 + 2 * WTOT) * 2;
    const int NB = (ws_size >= FULL4) ? 4 : 2;   // NB=2 path: 81.3 MB

    ushort_t* y1 = (ushort_t*)d_ws;              // [NB] planes, stride PLN32
    ushort_t* y2 = y1 + (size_t)NB * PLN32;
    ushort_t* wb = y2 + (size_t)NB * PLN32;
    ushort_t* w1h = wb;            ushort_t* w1l = w1h + W1SZ;
    ushort_t* w2h = w1l + W1SZ;    ushort_t* w2l = w2h + W2SZ;
    ushort_t* w3h = w2l + W2SZ;    ushort_t* w3l = w3h + W3SZ;
    ushort_t* fx  = y2;                          // fx aliases y2 region, stride PLN8
    float*    ksf = (float*)y1;                  // ks aliases y1 region, stride PLN32/2 f32

    const size_t KS_BSTR = PLN32 / 2;            // f32 units

    dim3 blk(256);
    wtrans_kernel<<<256, blk, 0, stream>>>(W1, w1h, w1l, 64, 256, 8, 64, (int)W1SZ);
    wtrans_kernel<<<256, blk, 0, stream>>>(W2, w2h, w2l, 256, 256, 32, 64, (int)W2SZ);
    wtrans_kernel<<<256, blk, 0, stream>>>(W3, w3h, w3l, 256, 75, 32, 32, (int)W3SZ);

    // MF=4: tile 16x32 -> 72 spatial blocks; grids carry NB batches in z
    dim3 g12(72, 4, NB), g3(72, 3, NB);
    dim3 ga((NB * PLANE + 255) / 256);
    for (int bp = 0; bp < 4 / NB; ++bp) {
        const float* fxsrc = feature_x + (size_t)bp * NB * 64 * PLANE;
        const float* x_b   = x   + (size_t)bp * NB * 3 * PLANE;
        float* out_b       = out + (size_t)bp * NB * 3 * PLANE;
        // Re-zero borders EVERY group: prev group's ks (aliasing y1) clobbered y1
        // borders with f32 bit patterns (bf16-NaN hazard, r15 lesson). zborder(y2)
        // also zeroes fx borders (fx planes = leading chunks of y2 region, same geometry).
        zborder_kernel<<<97, blk, 0, stream>>>(y1, NB * 32);
        zborder_kernel<<<97, blk, 0, stream>>>(y2, NB * 32);
        packfx_kernel<<<1024, blk, 0, stream>>>(fxsrc, fx, NB, PLN8);
        conv_mfma< 8, 64, 4, false><<<g12, blk, 0, stream>>>(
            fx, w1h, w1l, b1, 256, y1, nullptr, PLN8, PLN32, 0);
        conv_mfma<32, 64, 4, false><<<g12, blk, 0, stream>>>(
            y1, w2h, w2l, b2, 256, y2, nullptr, PLN32, PLN32, 0);
        conv_mfma<32, 32, 4, true ><<<g3, blk, 0, stream>>>(
            y2, w3h, w3l, b3, 75, nullptr, ksf, PLN32, 0, KS_BSTR);
        apply_kernel<<<ga, blk, 0, stream>>>(x_b, ksf, out_b, NB, KS_BSTR);
    }
}

// Round 18
// 489.836 us; speedup vs baseline: 3.0952x; 1.4107x over previous
//
#include <hip/hip_runtime.h>
#include <hip/hip_bf16.h>
#include <stdint.h>

#define HW 192
#define PLANE (HW * HW)
#define PH 194
#define PPG (PH * PH)      // 37636 granules per padded 8-ch plane

typedef __attribute__((ext_vector_type(8))) short frag8;
typedef __attribute__((ext_vector_type(16))) float f32x16;
typedef unsigned short ushort_t;

__device__ __forceinline__ ushort_t b16(float v) {
    __hip_bfloat16 b = __float2bfloat16(v);
    return __builtin_bit_cast(ushort_t, b);
}

// async 16B global->LDS copy: per-lane global src, wave-uniform LDS base (+lane*16)
__device__ __forceinline__ void gld_lds16(const ushort_t* g, ushort_t* s) {
    __builtin_amdgcn_global_load_lds(
        (const __attribute__((address_space(1))) uint32_t*)(const void*)g,
        (__attribute__((address_space(3))) uint32_t*)(void*)s, 16, 0, 0);
}

// W[O][C_IN][3][3] f32 -> wt [NOB][NCHUNK][10][OTC][8] bf16 (tap slot 9 and o>=C_OUT zero)
__global__ __launch_bounds__(256) void wtrans_kernel(
    const float* __restrict__ w, ushort_t* __restrict__ wt,
    int C_IN, int C_OUT, int NCHUNK, int OTC, int total)
{
    for (int idx = blockIdx.x * 256 + threadIdx.x; idx < total; idx += gridDim.x * 256) {
        int ic = idx & 7;
        int g = idx >> 3;
        int o = g % OTC; g /= OTC;
        int t = g % 10;  g /= 10;
        int c8 = g % NCHUNK;
        int ob = g / NCHUNK;
        int og = ob * OTC + o;
        float v = 0.f;
        if (t < 9 && og < C_OUT)
            v = w[((size_t)og * C_IN + c8 * 8 + ic) * 9 + t];
        wt[idx] = b16(v);
    }
}

// src [nb*64][H][W] f32 -> per-batch padded bf16 planes [8][PH][PH][8] at b*bstr
__global__ __launch_bounds__(256) void packfx_kernel(
    const float* __restrict__ src, ushort_t* __restrict__ d,
    int nb, size_t bstr)
{
    int n = nb * 64 * PLANE;
    for (int idx = blockIdx.x * 256 + threadIdx.x; idx < n; idx += gridDim.x * 256) {
        int c = idx / PLANE;
        int p = idx - c * PLANE;
        int b = c >> 6, cc = c & 63;
        int y = p / HW, x = p - y * HW;
        size_t di = (size_t)b * bstr + ((size_t)(cc >> 3) * PPG + (size_t)(y + 1) * PH + (x + 1)) * 8 + (cc & 7);
        d[di] = b16(src[idx]);
    }
}

// zero the 1-px borders of nchunks padded planes
__global__ __launch_bounds__(256) void zborder_kernel(
    ushort_t* __restrict__ ph, int nchunks)
{
    int total = nchunks * 772;
    for (int i = blockIdx.x * 256 + threadIdx.x; i < total; i += gridDim.x * 256) {
        int chunk = i / 772, b = i - chunk * 772;
        int y, x;
        if (b < 194)      { y = 0;   x = b; }
        else if (b < 388) { y = 193; x = b - 194; }
        else { int r = b - 388; y = 1 + (r >> 1); x = (r & 1) ? 193 : 0; }
        size_t g = ((size_t)chunk * PPG + (size_t)y * PH + x) * 8;
        *(uint4*)&ph[g] = make_uint4(0, 0, 0, 0);
    }
}

// 3x3 SAME conv, single-pass bf16 MFMA (32x32x16): A = bf16 activations,
// B = bf16 weights, one MFMA per k-step. blockIdx.z = batch within dispatch.
// inp: [NCHUNK][PH][PH][8] per batch (stride in_bstr ush); wt: [NOB][NCHUNK][10][OTC][8].
// Block: 256 thr (4 waves), (4*MF rows)x32 cols tile. Wave wv owns MF one-row m-frags
// (rows wv*MF..+MF-1); one-row frags are conflict-free A-reads (r13/r14-verified).
// Halo + weights double-buffered, ONE barrier per chunk (~40KB LDS at MF=4/OTC=64).
// K-step = 16 = 2 tap-slots x 8 ic; 10 tap-slots (slot 9 zero) -> 5 k-steps/chunk.
// A row / B col = lane&31; k-octet = lane>>5 (tap); same contiguous-8 k-labeling both
// sides -> HW k-permutation cancels. C/D: col=lane&31, m=(reg&3)+8(reg>>2)+4(lane>>5).
// NOTE: no min-waves hint (rounds 5/8: hint below acc footprint -> scratch spill).
template<int NCHUNK, int OTC, int MF, bool LAST>
__global__ __launch_bounds__(256) void conv_mfma(
    const ushort_t* __restrict__ inp, const ushort_t* __restrict__ wt,
    const float* __restrict__ bias, int c_out,
    ushort_t* __restrict__ outp, float* __restrict__ outf,
    size_t in_bstr, size_t out_bstr, size_t outf_bstr)
{
    constexpr int NF = OTC / 32;
    constexpr int TSY = 4 * MF;
    constexpr int HALR = TSY + 2;
    constexpr int HGR2 = HALR * 34;           // halo granules
    constexpr int NHI = (HGR2 + 63) / 64;     // halo staging iters
    constexpr int WGR = 10 * OTC;             // weight granules per chunk slab
    constexpr int NWI = WGR / 64;             // weight staging iters
    __shared__ ushort_t s_x[2 * HGR2 * 8];
    __shared__ ushort_t s_w[2 * WGR * 8];

    const int tid = threadIdx.x;
    const int wv = tid >> 6;          // 0..3
    const int lane = tid & 63;
    const int ln31 = lane & 31;       // A row (pixel col) / B col (o) / D col
    const int lhalf = lane >> 5;      // k-octet -> tap select within k-step
    const int tx0 = (blockIdx.x % 6) * 32;
    const int ty0 = (blockIdx.x / 6) * TSY;
    const int ob = blockIdx.y;
    const int bz = blockIdx.z;

    const ushort_t* bin = inp + (size_t)bz * in_bstr;

    // m-frag = one row of 32 px; wave wv owns rows wv*MF .. wv*MF+MF-1
    int pixbase[MF];
    #pragma unroll
    for (int mf = 0; mf < MF; ++mf)
        pixbase[mf] = ((wv * MF + mf) * 34 + ln31) * 8;

    // per-lane tap offset into halo + weight slot, per k-step
    int hof[5], wslot[5];
    #pragma unroll
    for (int ks = 0; ks < 5; ++ks) {
        int t = ks * 2 + lhalf;
        wslot[ks] = t;
        int te = t > 8 ? 8 : t;   // pad slot 9 reads tap8's (valid) address; B there is zero
        int dy = te >= 6 ? 2 : (te >= 3 ? 1 : 0);
        int dx = te - dy * 3;
        hof[ks] = (dy * 34 + dx) * 8;
    }

    f32x16 acc[MF][NF];
    #pragma unroll
    for (int mf = 0; mf < MF; ++mf)
        #pragma unroll
        for (int nf = 0; nf < NF; ++nf) {
            int o = ob * OTC + nf * 32 + ln31;
            float bv = (o < c_out) ? bias[o] : 0.f;
            #pragma unroll
            for (int r = 0; r < 16; ++r) acc[mf][nf][r] = bv;
        }

    const ushort_t* wbase = wt + (size_t)ob * NCHUNK * WGR * 8;

    auto stage = [&](int buf, int c8) {
        const ushort_t* ih = bin + (size_t)c8 * PPG * 8;
        ushort_t* dx = s_x + buf * (HGR2 * 8);
        for (int j = wv; j < NHI; j += 4) {
            int hg = j * 64 + lane;
            if (hg < HGR2) {
                int r = hg / 34, c = hg - r * 34;
                size_t sg = ((size_t)(ty0 + r) * PH + (tx0 + c)) * 8;
                gld_lds16(&ih[sg], &dx[j * 64 * 8]);
            }
        }
        const ushort_t* wch = wbase + (size_t)c8 * WGR * 8;
        ushort_t* dw = s_w + buf * (WGR * 8);
        for (int j = wv; j < NWI; j += 4)
            gld_lds16(&wch[(j * 64 + lane) * 8], &dw[j * 64 * 8]);
    };

    stage(0, 0);
    __syncthreads();   // drains vmcnt -> buf0 ready

    int cur = 0;
    for (int c8 = 0; c8 < NCHUNK; ++c8) {
        if (c8 + 1 < NCHUNK) stage(cur ^ 1, c8 + 1);   // async prefetch, other buffer

        const ushort_t* xh = s_x + cur * (HGR2 * 8);
        const ushort_t* wh = s_w + cur * (WGR * 8);
        #pragma unroll
        for (int ks = 0; ks < 5; ++ks) {
            frag8 bh[NF];
            #pragma unroll
            for (int nf = 0; nf < NF; ++nf)
                bh[nf] = *(const frag8*)&wh[(wslot[ks] * OTC + nf * 32 + ln31) * 8];
            #pragma unroll
            for (int mf = 0; mf < MF; ++mf) {
                frag8 ah = *(const frag8*)&xh[pixbase[mf] + hof[ks]];
                #pragma unroll
                for (int nf = 0; nf < NF; ++nf)
                    acc[mf][nf] = __builtin_amdgcn_mfma_f32_32x32x16_bf16(ah, bh[nf], acc[mf][nf], 0, 0, 0);
            }
        }
        __syncthreads();   // joins waves on cur + drains prefetch vmcnt -> next buf ready
        cur ^= 1;
    }

    // ---- epilogue: reg j=4i+r: px col m = 8i + 4*lhalf + r; row = wv*MF+mf ----
    #pragma unroll
    for (int mf = 0; mf < MF; ++mf) {
        int gy = ty0 + wv * MF + mf;
        #pragma unroll
        for (int nf = 0; nf < NF; ++nf) {
            int o = ob * OTC + nf * 32 + ln31;
            if (o < c_out) {
                #pragma unroll
                for (int i = 0; i < 4; ++i) {
                    int px = tx0 + i * 8 + lhalf * 4;
                    if constexpr (LAST) {
                        float* boutf = outf + (size_t)bz * outf_bstr;
                        float4 v = make_float4(acc[mf][nf][4 * i + 0], acc[mf][nf][4 * i + 1],
                                               acc[mf][nf][4 * i + 2], acc[mf][nf][4 * i + 3]);
                        *(float4*)&boutf[(size_t)o * PLANE + gy * HW + px] = v;
                    } else {
                        ushort_t* bout = outp + (size_t)bz * out_bstr;
                        size_t g0 = ((size_t)(o >> 3) * PPG + (size_t)(gy + 1) * PH + (px + 1)) * 8 + (o & 7);
                        #pragma unroll
                        for (int r = 0; r < 4; ++r)
                            bout[g0 + (size_t)r * 8] = b16(acc[mf][nf][4 * i + r]);
                    }
                }
            }
        }
    }
}

// nb batches. out[b,c,y,x] = sum_p ks_b[p*3+c, y, x] * xpad[b, c, y+p/5-2, x+p%5-2]
__global__ __launch_bounds__(256) void apply_kernel(
    const float* __restrict__ x, const float* __restrict__ ks,
    float* __restrict__ out, int nb, size_t ks_bstr)
{
    int tid = blockIdx.x * 256 + threadIdx.x;
    int total = nb * PLANE;
    if (tid >= total) return;
    int b = tid / PLANE;
    int pix = tid - b * PLANE;
    int y = pix / HW;
    int xc = pix - y * HW;

    const float* xb  = x  + (size_t)b * 3 * PLANE;
    const float* ksb = ks + (size_t)b * ks_bstr;
    float* ob        = out + (size_t)b * 3 * PLANE;

    float acc[3] = {0.f, 0.f, 0.f};
    #pragma unroll
    for (int p = 0; p < 25; ++p) {
        const int di = p / 5, dj = p % 5;
        int yy = y + di - 2, xx = xc + dj - 2;
        bool inb = (yy >= 0 && yy < HW && xx >= 0 && xx < HW);
        #pragma unroll
        for (int c = 0; c < 3; ++c) {
            float kv = ksb[((size_t)(p * 3 + c) * HW + y) * HW + xc];
            float xv = inb ? xb[((size_t)c * HW + yy) * HW + xx] : 0.f;
            acc[c] = fmaf(kv, xv, acc[c]);
        }
    }
    #pragma unroll
    for (int c = 0; c < 3; ++c)
        ob[((size_t)c * HW + y) * HW + xc] = acc[c];
}

extern "C" void kernel_launch(void* const* d_in, const int* in_sizes, int n_in,
                              void* d_out, int out_size, void* d_ws, size_t ws_size,
                              hipStream_t stream) {
    const float* feature_x = (const float*)d_in[0];
    const float* x  = (const float*)d_in[1];
    const float* W1 = (const float*)d_in[2];
    const float* b1 = (const float*)d_in[3];
    const float* W2 = (const float*)d_in[4];
    const float* b2 = (const float*)d_in[5];
    const float* W3 = (const float*)d_in[6];
    const float* b3 = (const float*)d_in[7];
    float* out = (float*)d_out;

    const size_t PLN32 = (size_t)32 * PPG * 8;   // 9,634,816 ush (single bf16 plane/batch)
    const size_t PLN8  = (size_t)8 * PPG * 8;    // 2,408,704 ush
    const size_t W1SZ = 163840, W2SZ = 655360, W3SZ = 245760;
    const size_t WTOT = W1SZ + W2SZ + W3SZ;      // 1,064,960 ush (single bf16 tensors)
    // NB=4: y1[4] + y2[4] + weights = 156,286,976 B <= 158,416,896 B proven (r16).
    const size_t FULL4 = (8 * PLN32 + WTOT) * 2;
    const int NB = (ws_size >= FULL4) ? 4 : 2;   // NB=2 path: 79.2 MB

    ushort_t* y1 = (ushort_t*)d_ws;              // [NB] planes, stride PLN32
    ushort_t* y2 = y1 + (size_t)NB * PLN32;
    ushort_t* wb = y2 + (size_t)NB * PLN32;
    ushort_t* w1 = wb;
    ushort_t* w2 = w1 + W1SZ;
    ushort_t* w3 = w2 + W2SZ;
    ushort_t* fx  = y2;                          // fx aliases y2 region, stride PLN8
    float*    ksf = (float*)y1;                  // ks aliases y1 region, stride PLN32/2 f32

    const size_t KS_BSTR = PLN32 / 2;            // f32 units

    dim3 blk(256);
    wtrans_kernel<<<256, blk, 0, stream>>>(W1, w1, 64, 256, 8, 64, (int)W1SZ);
    wtrans_kernel<<<256, blk, 0, stream>>>(W2, w2, 256, 256, 32, 64, (int)W2SZ);
    wtrans_kernel<<<256, blk, 0, stream>>>(W3, w3, 256, 75, 32, 32, (int)W3SZ);

    // MF=4: tile 16x32 -> 72 spatial blocks; grids carry NB batches in z
    dim3 g12(72, 4, NB), g3(72, 3, NB);
    dim3 ga((NB * PLANE + 255) / 256);
    for (int bp = 0; bp < 4 / NB; ++bp) {
        const float* fxsrc = feature_x + (size_t)bp * NB * 64 * PLANE;
        const float* x_b   = x   + (size_t)bp * NB * 3 * PLANE;
        float* out_b       = out + (size_t)bp * NB * 3 * PLANE;
        // Re-zero borders EVERY group: prev group's ks (aliasing y1) clobbered y1
        // borders with f32 bit patterns (bf16-NaN hazard, r15 lesson). zborder(y2)
        // also zeroes fx borders (fx planes = leading chunks of y2 region, same geometry).
        zborder_kernel<<<97, blk, 0, stream>>>(y1, NB * 32);
        zborder_kernel<<<97, blk, 0, stream>>>(y2, NB * 32);
        packfx_kernel<<<1024, blk, 0, stream>>>(fxsrc, fx, NB, PLN8);
        conv_mfma< 8, 64, 4, false><<<g12, blk, 0, stream>>>(
            fx, w1, b1, 256, y1, nullptr, PLN8, PLN32, 0);
        conv_mfma<32, 64, 4, false><<<g12, blk, 0, stream>>>(
            y1, w2, b2, 256, y2, nullptr, PLN32, PLN32, 0);
        conv_mfma<32, 32, 4, true ><<<g3, blk, 0, stream>>>(
            y2, w3, b3, 75, nullptr, ksf, PLN32, 0, KS_BSTR);
        apply_kernel<<<ga, blk, 0, stream>>>(x_b, ksf, out_b, NB, KS_BSTR);
    }
}

// Round 19
// 424.607 us; speedup vs baseline: 3.5707x; 1.1536x over previous
//
#include <hip/hip_runtime.h>
#include <hip/hip_bf16.h>
#include <stdint.h>

#define HW 192
#define PLANE (HW * HW)
#define PH 194
#define PPG (PH * PH)      // 37636 granules per padded 8-ch plane

typedef __attribute__((ext_vector_type(8))) short frag8;
typedef __attribute__((ext_vector_type(16))) float f32x16;
typedef unsigned short ushort_t;

__device__ __forceinline__ ushort_t b16(float v) {
    __hip_bfloat16 b = __float2bfloat16(v);
    return __builtin_bit_cast(ushort_t, b);
}

// async 16B global->LDS copy: per-lane global src, wave-uniform LDS base (+lane*16)
__device__ __forceinline__ void gld_lds16(const ushort_t* g, ushort_t* s) {
    __builtin_amdgcn_global_load_lds(
        (const __attribute__((address_space(1))) uint32_t*)(const void*)g,
        (__attribute__((address_space(3))) uint32_t*)(void*)s, 16, 0, 0);
}

template<int N> __device__ __forceinline__ void vmcnt_wait() {
    static_assert(N == 0 || N == 5 || N == 6, "unsupported vmcnt");
    if constexpr (N == 0) asm volatile("s_waitcnt vmcnt(0)" ::: "memory");
    else if constexpr (N == 5) asm volatile("s_waitcnt vmcnt(5)" ::: "memory");
    else if constexpr (N == 6) asm volatile("s_waitcnt vmcnt(6)" ::: "memory");
}

// W[O][C_IN][3][3] f32 -> wt [NOB][NCHUNK][10][OTC][8] bf16 (tap slot 9 and o>=C_OUT zero)
__global__ __launch_bounds__(256) void wtrans_kernel(
    const float* __restrict__ w, ushort_t* __restrict__ wt,
    int C_IN, int C_OUT, int NCHUNK, int OTC, int total)
{
    for (int idx = blockIdx.x * 256 + threadIdx.x; idx < total; idx += gridDim.x * 256) {
        int ic = idx & 7;
        int g = idx >> 3;
        int o = g % OTC; g /= OTC;
        int t = g % 10;  g /= 10;
        int c8 = g % NCHUNK;
        int ob = g / NCHUNK;
        int og = ob * OTC + o;
        float v = 0.f;
        if (t < 9 && og < C_OUT)
            v = w[((size_t)og * C_IN + c8 * 8 + ic) * 9 + t];
        wt[idx] = b16(v);
    }
}

// src [nb*64][H][W] f32 -> per-batch padded bf16 planes [8][PH][PH][8] at b*bstr
__global__ __launch_bounds__(256) void packfx_kernel(
    const float* __restrict__ src, ushort_t* __restrict__ d,
    int nb, size_t bstr)
{
    int n = nb * 64 * PLANE;
    for (int idx = blockIdx.x * 256 + threadIdx.x; idx < n; idx += gridDim.x * 256) {
        int c = idx / PLANE;
        int p = idx - c * PLANE;
        int b = c >> 6, cc = c & 63;
        int y = p / HW, x = p - y * HW;
        size_t di = (size_t)b * bstr + ((size_t)(cc >> 3) * PPG + (size_t)(y + 1) * PH + (x + 1)) * 8 + (cc & 7);
        d[di] = b16(src[idx]);
    }
}

// zero the 1-px borders of nchunks padded planes
__global__ __launch_bounds__(256) void zborder_kernel(
    ushort_t* __restrict__ ph, int nchunks)
{
    int total = nchunks * 772;
    for (int i = blockIdx.x * 256 + threadIdx.x; i < total; i += gridDim.x * 256) {
        int chunk = i / 772, b = i - chunk * 772;
        int y, x;
        if (b < 194)      { y = 0;   x = b; }
        else if (b < 388) { y = 193; x = b - 194; }
        else { int r = b - 388; y = 1 + (r >> 1); x = (r & 1) ? 193 : 0; }
        size_t g = ((size_t)chunk * PPG + (size_t)y * PH + x) * 8;
        *(uint4*)&ph[g] = make_uint4(0, 0, 0, 0);
    }
}

// 3x3 SAME conv, single-pass bf16 MFMA (32x32x16), T4 counted-vmcnt pipeline:
// raw s_barrier + s_waitcnt vmcnt(L) — prefetch loads stay in flight across the
// barrier (never drained to 0 in the loop). Every wave issues EXACTLY L loads per
// chunk (iters padded; OOB lanes clamp the GLOBAL address and land in LDS pad that
// is never read) so the per-wave vmcnt immediate is uniform.
// inp: [NCHUNK][PH][PH][8] per batch; wt: [NOB][NCHUNK][10][OTC][8]. blockIdx.z=batch.
// Block: 256 thr (4 waves), 16x32 tile, MF=4 one-row m-frags/wave (conflict-free).
// K-step = 16 = 2 tap-slots x 8 ic; 10 tap-slots (slot 9 zero) -> 5 k-steps/chunk.
// A row / B col = lane&31; k-octet = lane>>5 (tap); same contiguous-8 k-labeling both
// sides -> HW k-permutation cancels. C/D: col=lane&31, m=(reg&3)+8(reg>>2)+4(lane>>5).
// NOTE: no min-waves hint (rounds 5/8: hint below acc footprint -> scratch spill).
template<int NCHUNK, int OTC, bool LAST>
__global__ __launch_bounds__(256) void conv_mfma(
    const ushort_t* __restrict__ inp, const ushort_t* __restrict__ wt,
    const float* __restrict__ bias, int c_out,
    ushort_t* __restrict__ outp, float* __restrict__ outf,
    size_t in_bstr, size_t out_bstr, size_t outf_bstr)
{
    constexpr int MF = 4;
    constexpr int NF = OTC / 32;
    constexpr int HGR2 = 18 * 34;             // 612 halo granules (16x32 tile + halo)
    constexpr int HITER = 3;                  // 12 padded halo iters / 4 waves
    constexpr int HPADG = 12 * 64;            // 768 LDS granules per halo buffer
    constexpr int WGR = 10 * OTC;             // weight granules per chunk slab
    constexpr int WITER = (OTC == 64) ? 3 : 2;    // padded weight iters / wave
    constexpr int WPADG = WITER * 4 * 64;     // LDS granules per weight buffer
    constexpr int L = HITER + WITER;          // loads per wave per chunk (6 or 5)
    __shared__ ushort_t s_x[2 * HPADG * 8];
    __shared__ ushort_t s_w[2 * WPADG * 8];

    const int tid = threadIdx.x;
    const int wv = tid >> 6;          // 0..3
    const int lane = tid & 63;
    const int ln31 = lane & 31;       // A row (pixel col) / B col (o) / D col
    const int lhalf = lane >> 5;      // k-octet -> tap select within k-step
    const int tx0 = (blockIdx.x % 6) * 32;
    const int ty0 = (blockIdx.x / 6) * 16;
    const int ob = blockIdx.y;
    const int bz = blockIdx.z;

    const ushort_t* bin = inp + (size_t)bz * in_bstr;

    // m-frag = one row of 32 px; wave wv owns rows wv*MF .. wv*MF+MF-1
    int pixbase[MF];
    #pragma unroll
    for (int mf = 0; mf < MF; ++mf)
        pixbase[mf] = ((wv * MF + mf) * 34 + ln31) * 8;

    // per-lane tap offset into halo + weight slot, per k-step
    int hof[5], wslot[5];
    #pragma unroll
    for (int ks = 0; ks < 5; ++ks) {
        int t = ks * 2 + lhalf;
        wslot[ks] = t;
        int te = t > 8 ? 8 : t;   // pad slot 9 reads tap8's (valid) address; B there is zero
        int dy = te >= 6 ? 2 : (te >= 3 ? 1 : 0);
        int dx = te - dy * 3;
        hof[ks] = (dy * 34 + dx) * 8;
    }

    f32x16 acc[MF][NF];
    #pragma unroll
    for (int mf = 0; mf < MF; ++mf)
        #pragma unroll
        for (int nf = 0; nf < NF; ++nf) {
            int o = ob * OTC + nf * 32 + ln31;
            float bv = (o < c_out) ? bias[o] : 0.f;
            #pragma unroll
            for (int r = 0; r < 16; ++r) acc[mf][nf][r] = bv;
        }

    const ushort_t* wbase = wt + (size_t)ob * NCHUNK * WGR * 8;

    // exactly L gld_lds per wave per call (clamped, no divergent skips)
    auto stage = [&](int buf, int c8) {
        const ushort_t* ih = bin + (size_t)c8 * PPG * 8;
        ushort_t* dx = s_x + buf * (HPADG * 8);
        #pragma unroll
        for (int i = 0; i < HITER; ++i) {
            int j = wv * HITER + i;
            int hg = j * 64 + lane;
            int hgc = hg < HGR2 ? hg : HGR2 - 1;   // clamp: pad lanes re-load last granule
            int r = hgc / 34, c = hgc - r * 34;
            size_t sg = ((size_t)(ty0 + r) * PH + (tx0 + c)) * 8;
            gld_lds16(&ih[sg], &dx[j * 64 * 8]);
        }
        const ushort_t* wch = wbase + (size_t)c8 * WGR * 8;
        ushort_t* dw = s_w + buf * (WPADG * 8);
        #pragma unroll
        for (int i = 0; i < WITER; ++i) {
            int j = wv * WITER + i;
            int wg = j * 64 + lane;
            int wgc = wg < WGR ? wg : WGR - 1;
            gld_lds16(&wch[(size_t)wgc * 8], &dw[j * 64 * 8]);
        }
    };

    // prologue: chunks 0 and 1 in flight; wait for chunk 0 only
    stage(0, 0);
    if (NCHUNK > 1) stage(1, 1);
    vmcnt_wait<0>();   // NCHUNK==8/32 both >1, but chunk0 must be complete; L would
                       // leave chunk1 flying — chunk0 is the older L, so vmcnt(L) is
                       // correct; use it when NCHUNK>1:
    // (note: the line above drained everything for simplicity/safety at prologue only)
    __builtin_amdgcn_s_barrier();
    __builtin_amdgcn_sched_barrier(0);

    for (int c8 = 0; c8 < NCHUNK; ++c8) {
        const int cur = c8 & 1;
        const ushort_t* xh = s_x + cur * (HPADG * 8);
        const ushort_t* wh = s_w + cur * (WPADG * 8);
        #pragma unroll
        for (int ks = 0; ks < 5; ++ks) {
            frag8 bh[NF];
            #pragma unroll
            for (int nf = 0; nf < NF; ++nf)
                bh[nf] = *(const frag8*)&wh[(wslot[ks] * OTC + nf * 32 + ln31) * 8];
            #pragma unroll
            for (int mf = 0; mf < MF; ++mf) {
                frag8 ah = *(const frag8*)&xh[pixbase[mf] + hof[ks]];
                #pragma unroll
                for (int nf = 0; nf < NF; ++nf)
                    acc[mf][nf] = __builtin_amdgcn_mfma_f32_32x32x16_bf16(ah, bh[nf], acc[mf][nf], 0, 0, 0);
            }
        }
        if (c8 + 1 == NCHUNK) break;
        __builtin_amdgcn_sched_barrier(0);
        __builtin_amdgcn_s_barrier();          // A: all waves done reading buf[cur]
        if (c8 + 2 < NCHUNK) {
            stage(cur, c8 + 2);                // overwrite buf[cur] with chunk c8+2
            if constexpr (OTC == 64) vmcnt_wait<6>(); else vmcnt_wait<5>();
        } else {
            vmcnt_wait<0>();                   // tail: nothing new issued
        }
        __builtin_amdgcn_s_barrier();          // B: chunk c8+1's loads have landed
        __builtin_amdgcn_sched_barrier(0);
    }

    // ---- epilogue: reg j=4i+r: px col m = 8i + 4*lhalf + r; row = wv*MF+mf ----
    #pragma unroll
    for (int mf = 0; mf < MF; ++mf) {
        int gy = ty0 + wv * MF + mf;
        #pragma unroll
        for (int nf = 0; nf < NF; ++nf) {
            int o = ob * OTC + nf * 32 + ln31;
            if (o < c_out) {
                #pragma unroll
                for (int i = 0; i < 4; ++i) {
                    int px = tx0 + i * 8 + lhalf * 4;
                    if constexpr (LAST) {
                        float* boutf = outf + (size_t)bz * outf_bstr;
                        float4 v = make_float4(acc[mf][nf][4 * i + 0], acc[mf][nf][4 * i + 1],
                                               acc[mf][nf][4 * i + 2], acc[mf][nf][4 * i + 3]);
                        *(float4*)&boutf[(size_t)o * PLANE + gy * HW + px] = v;
                    } else {
                        ushort_t* bout = outp + (size_t)bz * out_bstr;
                        size_t g0 = ((size_t)(o >> 3) * PPG + (size_t)(gy + 1) * PH + (px + 1)) * 8 + (o & 7);
                        #pragma unroll
                        for (int r = 0; r < 4; ++r)
                            bout[g0 + (size_t)r * 8] = b16(acc[mf][nf][4 * i + r]);
                    }
                }
            }
        }
    }
}

// nb batches. out[b,c,y,x] = sum_p ks_b[p*3+c, y, x] * xpad[b, c, y+p/5-2, x+p%5-2]
__global__ __launch_bounds__(256) void apply_kernel(
    const float* __restrict__ x, const float* __restrict__ ks,
    float* __restrict__ out, int nb, size_t ks_bstr)
{
    int tid = blockIdx.x * 256 + threadIdx.x;
    int total = nb * PLANE;
    if (tid >= total) return;
    int b = tid / PLANE;
    int pix = tid - b * PLANE;
    int y = pix / HW;
    int xc = pix - y * HW;

    const float* xb  = x  + (size_t)b * 3 * PLANE;
    const float* ksb = ks + (size_t)b * ks_bstr;
    float* ob        = out + (size_t)b * 3 * PLANE;

    float acc[3] = {0.f, 0.f, 0.f};
    #pragma unroll
    for (int p = 0; p < 25; ++p) {
        const int di = p / 5, dj = p % 5;
        int yy = y + di - 2, xx = xc + dj - 2;
        bool inb = (yy >= 0 && yy < HW && xx >= 0 && xx < HW);
        #pragma unroll
        for (int c = 0; c < 3; ++c) {
            float kv = ksb[((size_t)(p * 3 + c) * HW + y) * HW + xc];
            float xv = inb ? xb[((size_t)c * HW + yy) * HW + xx] : 0.f;
            acc[c] = fmaf(kv, xv, acc[c]);
        }
    }
    #pragma unroll
    for (int c = 0; c < 3; ++c)
        ob[((size_t)c * HW + y) * HW + xc] = acc[c];
}

extern "C" void kernel_launch(void* const* d_in, const int* in_sizes, int n_in,
                              void* d_out, int out_size, void* d_ws, size_t ws_size,
                              hipStream_t stream) {
    const float* feature_x = (const float*)d_in[0];
    const float* x  = (const float*)d_in[1];
    const float* W1 = (const float*)d_in[2];
    const float* b1 = (const float*)d_in[3];
    const float* W2 = (const float*)d_in[4];
    const float* b2 = (const float*)d_in[5];
    const float* W3 = (const float*)d_in[6];
    const float* b3 = (const float*)d_in[7];
    float* out = (float*)d_out;

    const size_t PLN32 = (size_t)32 * PPG * 8;   // 9,634,816 ush (single bf16 plane/batch)
    const size_t PLN8  = (size_t)8 * PPG * 8;    // 2,408,704 ush
    const size_t W1SZ = 163840, W2SZ = 655360, W3SZ = 245760;
    const size_t WTOT = W1SZ + W2SZ + W3SZ;      // 1,064,960 ush
    // NB=4: y1[4] + y2[4] + weights = 156,286,976 B <= 158,416,896 B proven (r16).
    const size_t FULL4 = (8 * PLN32 + WTOT) * 2;
    const int NB = (ws_size >= FULL4) ? 4 : 2;   // NB=2 path: 79.2 MB

    ushort_t* y1 = (ushort_t*)d_ws;              // [NB] planes, stride PLN32
    ushort_t* y2 = y1 + (size_t)NB * PLN32;
    ushort_t* wb = y2 + (size_t)NB * PLN32;
    ushort_t* w1 = wb;
    ushort_t* w2 = w1 + W1SZ;
    ushort_t* w3 = w2 + W2SZ;
    ushort_t* fx  = y2;                          // fx aliases y2 region, stride PLN8
    float*    ksf = (float*)y1;                  // ks aliases y1 region, stride PLN32/2 f32

    const size_t KS_BSTR = PLN32 / 2;            // f32 units

    dim3 blk(256);
    wtrans_kernel<<<256, blk, 0, stream>>>(W1, w1, 64, 256, 8, 64, (int)W1SZ);
    wtrans_kernel<<<256, blk, 0, stream>>>(W2, w2, 256, 256, 32, 64, (int)W2SZ);
    wtrans_kernel<<<256, blk, 0, stream>>>(W3, w3, 256, 75, 32, 32, (int)W3SZ);

    // MF=4: tile 16x32 -> 72 spatial blocks; grids carry NB batches in z
    dim3 g12(72, 4, NB), g3(72, 3, NB);
    dim3 ga((NB * PLANE + 255) / 256);
    for (int bp = 0; bp < 4 / NB; ++bp) {
        const float* fxsrc = feature_x + (size_t)bp * NB * 64 * PLANE;
        const float* x_b   = x   + (size_t)bp * NB * 3 * PLANE;
        float* out_b       = out + (size_t)bp * NB * 3 * PLANE;
        // Re-zero borders EVERY group: prev group's ks (aliasing y1) clobbered y1
        // borders with f32 bit patterns (bf16-NaN hazard, r15 lesson). zborder(y2)
        // also zeroes fx borders (fx planes = leading chunks of y2 region, same geometry).
        zborder_kernel<<<97, blk, 0, stream>>>(y1, NB * 32);
        zborder_kernel<<<97, blk, 0, stream>>>(y2, NB * 32);
        packfx_kernel<<<1024, blk, 0, stream>>>(fxsrc, fx, NB, PLN8);
        conv_mfma< 8, 64, false><<<g12, blk, 0, stream>>>(
            fx, w1, b1, 256, y1, nullptr, PLN8, PLN32, 0);
        conv_mfma<32, 64, false><<<g12, blk, 0, stream>>>(
            y1, w2, b2, 256, y2, nullptr, PLN32, PLN32, 0);
        conv_mfma<32, 32, true ><<<g3, blk, 0, stream>>>(
            y2, w3, b3, 75, nullptr, ksf, PLN32, 0, KS_BSTR);
        apply_kernel<<<ga, blk, 0, stream>>>(x_b, ksf, out_b, NB, KS_BSTR);
    }
}